// Round 1
// baseline (763.380 us; speedup 1.0000x reference)
//
#include <hip/hip_runtime.h>
#include <cstddef>

// ---------------------------------------------------------------------------
// Problem constants (from reference): B=2, S=2048, D=1024, H=16, KVH=4, hd=64
// window_size read from device (d_in[9]).
// ---------------------------------------------------------------------------

// ---------------- fp32 GEMM: C[M,N] = A[M,K] @ W[K,N] ----------------------
// 128x128 tile, 256 threads, 8x8 micro-tile. M,N multiples of 128; K mult 16.
__global__ __launch_bounds__(256) void gemm_f32(
    const float* __restrict__ A, const float* __restrict__ W,
    float* __restrict__ C, int K, int lda, int ldw, int ldc)
{
  __shared__ float As[16][132];   // [kk][row], padded
  __shared__ float Bs[16][132];   // [kk][col], padded
  const int t  = threadIdx.x;
  const int tx = t & 15, ty = t >> 4;
  const int m0 = blockIdx.x * 128, n0 = blockIdx.y * 128;

  float acc[8][8];
#pragma unroll
  for (int r = 0; r < 8; ++r)
#pragma unroll
    for (int c = 0; c < 8; ++c) acc[r][c] = 0.f;

  const int arow = t >> 2, ac4 = t & 3;   // A loader: rows arow, arow+64
  const int bkk  = t >> 5, bc4 = t & 31;  // B loader: kk bkk, bkk+8

  for (int k0 = 0; k0 < K; k0 += 16) {
    float4 a0 = *(const float4*)(A + (size_t)(m0 + arow)      * lda + k0 + ac4 * 4);
    float4 a1 = *(const float4*)(A + (size_t)(m0 + arow + 64) * lda + k0 + ac4 * 4);
    float4 b0 = *(const float4*)(W + (size_t)(k0 + bkk)     * ldw + n0 + bc4 * 4);
    float4 b1 = *(const float4*)(W + (size_t)(k0 + bkk + 8) * ldw + n0 + bc4 * 4);
    // store A transposed [kk][row]
    As[ac4*4+0][arow] = a0.x; As[ac4*4+1][arow] = a0.y;
    As[ac4*4+2][arow] = a0.z; As[ac4*4+3][arow] = a0.w;
    As[ac4*4+0][arow+64] = a1.x; As[ac4*4+1][arow+64] = a1.y;
    As[ac4*4+2][arow+64] = a1.z; As[ac4*4+3][arow+64] = a1.w;
    *(float4*)&Bs[bkk][bc4*4]   = b0;
    *(float4*)&Bs[bkk+8][bc4*4] = b1;
    __syncthreads();
#pragma unroll
    for (int kk = 0; kk < 16; ++kk) {
      float4 x0 = *(const float4*)&As[kk][ty*8];
      float4 x1 = *(const float4*)&As[kk][ty*8+4];
      float4 y0 = *(const float4*)&Bs[kk][tx*8];
      float4 y1 = *(const float4*)&Bs[kk][tx*8+4];
      float ar[8] = {x0.x,x0.y,x0.z,x0.w,x1.x,x1.y,x1.z,x1.w};
      float br[8] = {y0.x,y0.y,y0.z,y0.w,y1.x,y1.y,y1.z,y1.w};
#pragma unroll
      for (int r = 0; r < 8; ++r)
#pragma unroll
        for (int c = 0; c < 8; ++c) acc[r][c] += ar[r] * br[c];
    }
    __syncthreads();
  }
#pragma unroll
  for (int r = 0; r < 8; ++r) {
    float4 o0, o1;
    o0.x = acc[r][0]; o0.y = acc[r][1]; o0.z = acc[r][2]; o0.w = acc[r][3];
    o1.x = acc[r][4]; o1.y = acc[r][5]; o1.z = acc[r][6]; o1.w = acc[r][7];
    float* cp = C + (size_t)(m0 + ty*8 + r) * ldc + n0 + tx*8;
    *(float4*)cp       = o0;
    *(float4*)(cp + 4) = o1;
  }
}

// ---------------- postprocess: ve-gate on V, rope+rmsnorm on Q,K -----------
// grid = B*S blocks, 256 threads (4 waves). 24 head-tasks per (b,s).
__global__ __launch_bounds__(256) void postproc(
    float* __restrict__ qws, float* __restrict__ kws, float* __restrict__ vws,
    const float* __restrict__ x, const float* __restrict__ ve,
    const float* __restrict__ cosp, const float* __restrict__ sinp,
    const float* __restrict__ Wg)
{
  const int bs = blockIdx.x;          // b*2048 + s
  const int s  = bs & 2047;
  const int t = threadIdx.x;
  const int wave = t >> 6, lane = t & 63;
  const int j = lane & 31;
  const float c  = cosp[s*32 + j];
  const float sn = sinp[s*32 + j];

  for (int task = wave; task < 24; task += 4) {
    if (task < 16) {                  // q head
      const size_t base = (size_t)bs * 1024 + task * 64 + lane;
      float val = qws[base];
      float other = __shfl_xor(val, 32);
      float rot = (lane < 32) ? (val * c + other * sn) : (val * c - other * sn);
      float ss = rot * rot;
#pragma unroll
      for (int m = 1; m < 64; m <<= 1) ss += __shfl_xor(ss, m);
      float rs = rsqrtf(ss * (1.0f/64.0f) + 1e-6f) * 1.2f;
      qws[base] = rot * rs;
    } else if (task < 20) {           // k head
      const int hk = task - 16;
      const size_t base = (size_t)bs * 256 + hk * 64 + lane;
      float val = kws[base];
      float other = __shfl_xor(val, 32);
      float rot = (lane < 32) ? (val * c + other * sn) : (val * c - other * sn);
      float ss = rot * rot;
#pragma unroll
      for (int m = 1; m < 64; m <<= 1) ss += __shfl_xor(ss, m);
      float rs = rsqrtf(ss * (1.0f/64.0f) + 1e-6f) * 1.2f;
      kws[base] = rot * rs;
    } else {                          // v head: += 3*sigmoid(x[:12]@Wg)*ve
      const int kvh = task - 20;
      float g = 0.f;
#pragma unroll
      for (int i = 0; i < 12; ++i) g += x[(size_t)bs * 1024 + i] * Wg[i * 4 + kvh];
      const float gate = 3.0f / (1.0f + __expf(-g));
      const size_t base = (size_t)bs * 256 + kvh * 64 + lane;
      vws[base] = vws[base] + gate * ve[base];
    }
  }
}

// ---------------- sliding-window causal GQA attention (fp32 flash) ---------
// grid = (S/64, H, B), 256 threads. Q-tile 64 rows; key tiles of 64,
// kt in [max(0,qt-8), qt] covers window 512.
__global__ __launch_bounds__(256) void attn_swa(
    const float* __restrict__ qg, const float* __restrict__ kg,
    const float* __restrict__ vg, float* __restrict__ yg,
    const int* __restrict__ wptr)
{
  __shared__ float qs[64][68];   // [d][row]  (transposed)
  __shared__ float kp[64][68];   // scores phase: K^T [d][key]; then P [row][key]
  __shared__ float vs[64][68];   // [key][d]
  const int qt = blockIdx.x, h = blockIdx.y, b = blockIdx.z;
  const int Wwin = *wptr;
  const int kvh = h >> 2;        // H/KVH = 4 (jnp.repeat -> h//4)
  const int q0 = qt * 64;
  const int t = threadIdx.x, tx = t & 15, ty = t >> 4;

  for (int u = t; u < 1024; u += 256) {
    const int row = u >> 4, c4 = u & 15;
    float4 qv = *(const float4*)(qg + ((size_t)(b*2048 + q0 + row))*1024 + h*64 + c4*4);
    qs[c4*4+0][row] = qv.x; qs[c4*4+1][row] = qv.y;
    qs[c4*4+2][row] = qv.z; qs[c4*4+3][row] = qv.w;
  }

  float m_r[4], l_r[4], acc[4][4];
#pragma unroll
  for (int r = 0; r < 4; ++r) {
    m_r[r] = -1e30f; l_r[r] = 0.f;
#pragma unroll
    for (int c = 0; c < 4; ++c) acc[r][c] = 0.f;
  }

  const int kt0 = (qt >= 8) ? (qt - 8) : 0;
  for (int kt = kt0; kt <= qt; ++kt) {
    for (int u = t; u < 1024; u += 256) {
      const int row = u >> 4, c4 = u & 15;
      const size_t gb = ((size_t)(b*2048 + kt*64 + row))*256 + kvh*64 + c4*4;
      float4 kv = *(const float4*)(kg + gb);
      float4 vv = *(const float4*)(vg + gb);
      kp[c4*4+0][row] = kv.x; kp[c4*4+1][row] = kv.y;
      kp[c4*4+2][row] = kv.z; kp[c4*4+3][row] = kv.w;
      *(float4*)&vs[row][c4*4] = vv;
    }
    __syncthreads();

    float s[4][4];
#pragma unroll
    for (int r = 0; r < 4; ++r)
#pragma unroll
      for (int c = 0; c < 4; ++c) s[r][c] = 0.f;
#pragma unroll 8
    for (int d = 0; d < 64; ++d) {
      float4 qv = *(const float4*)&qs[d][ty*4];
      float4 kv = *(const float4*)&kp[d][tx*4];
      float qr[4] = {qv.x, qv.y, qv.z, qv.w};
      float kr[4] = {kv.x, kv.y, kv.z, kv.w};
#pragma unroll
      for (int r = 0; r < 4; ++r)
#pragma unroll
        for (int c = 0; c < 4; ++c) s[r][c] += qr[r] * kr[c];
    }
    __syncthreads();   // done reading kp as K; about to overwrite with P

#pragma unroll
    for (int r = 0; r < 4; ++r) {
      const int qrow = q0 + ty*4 + r;
      float sv[4];
#pragma unroll
      for (int c = 0; c < 4; ++c) {
        const int kcol = kt*64 + tx*4 + c;
        const bool ok = (kcol <= qrow) && (kcol > qrow - Wwin);
        sv[c] = ok ? s[r][c] * 0.125f : -1e30f;
      }
      float mt = fmaxf(fmaxf(sv[0], sv[1]), fmaxf(sv[2], sv[3]));
      mt = fmaxf(mt, __shfl_xor(mt, 1));
      mt = fmaxf(mt, __shfl_xor(mt, 2));
      mt = fmaxf(mt, __shfl_xor(mt, 4));
      mt = fmaxf(mt, __shfl_xor(mt, 8));
      const float mn = fmaxf(m_r[r], mt);
      const float al = __expf(m_r[r] - mn);   // exp(0)=1 when both -1e30: self-heals
      float psum = 0.f;
#pragma unroll
      for (int c = 0; c < 4; ++c) {
        const float p = __expf(sv[c] - mn);
        kp[ty*4 + r][tx*4 + c] = p;
        psum += p;
      }
      psum += __shfl_xor(psum, 1);
      psum += __shfl_xor(psum, 2);
      psum += __shfl_xor(psum, 4);
      psum += __shfl_xor(psum, 8);
      l_r[r] = l_r[r] * al + psum;
      m_r[r] = mn;
#pragma unroll
      for (int c = 0; c < 4; ++c) acc[r][c] *= al;
    }
    __syncthreads();   // P visible to all

#pragma unroll 4
    for (int k4 = 0; k4 < 16; ++k4) {
      float pr[4][4], vr[4][4];
#pragma unroll
      for (int r = 0; r < 4; ++r) {
        float4 pv = *(const float4*)&kp[ty*4 + r][k4*4];
        pr[r][0] = pv.x; pr[r][1] = pv.y; pr[r][2] = pv.z; pr[r][3] = pv.w;
      }
#pragma unroll
      for (int jj = 0; jj < 4; ++jj) {
        float4 vv = *(const float4*)&vs[k4*4 + jj][tx*4];
        vr[jj][0] = vv.x; vr[jj][1] = vv.y; vr[jj][2] = vv.z; vr[jj][3] = vv.w;
      }
#pragma unroll
      for (int r = 0; r < 4; ++r)
#pragma unroll
        for (int jj = 0; jj < 4; ++jj)
#pragma unroll
          for (int c = 0; c < 4; ++c) acc[r][c] += pr[r][jj] * vr[jj][c];
    }
    __syncthreads();   // before next tile overwrites kp/vs
  }

#pragma unroll
  for (int r = 0; r < 4; ++r) {
    const float inv = 1.0f / l_r[r];
    float4 o;
    o.x = acc[r][0]*inv; o.y = acc[r][1]*inv; o.z = acc[r][2]*inv; o.w = acc[r][3]*inv;
    *(float4*)(yg + ((size_t)(b*2048 + q0 + ty*4 + r))*1024 + h*64 + tx*4) = o;
  }
}

// ---------------------------------------------------------------------------
extern "C" void kernel_launch(void* const* d_in, const int* in_sizes, int n_in,
                              void* d_out, int out_size, void* d_ws, size_t ws_size,
                              hipStream_t stream)
{
  const float* x    = (const float*)d_in[0];   // (2,2048,1024)
  const float* ve   = (const float*)d_in[1];   // (2,2048,256)
  const float* cosp = (const float*)d_in[2];   // (2048,1,32)
  const float* sinp = (const float*)d_in[3];
  const float* Wq   = (const float*)d_in[4];   // (1024,1024)
  const float* Wk   = (const float*)d_in[5];   // (1024,256)
  const float* Wv   = (const float*)d_in[6];   // (1024,256)
  const float* Wo   = (const float*)d_in[7];   // (1024,1024)
  const float* Wg   = (const float*)d_in[8];   // (12,4)
  const int*   win  = (const int*)d_in[9];     // scalar 512
  float* out = (float*)d_out;

  float* ws  = (float*)d_ws;
  float* qws = ws;                  // 4,194,304 floats (B,S,H,hd)
  float* kws = qws + 4194304;       // 1,048,576 floats (B,S,KVH,hd)
  float* vws = kws + 1048576;       // 1,048,576 floats
  float* yws = vws + 1048576;       // 4,194,304 floats (B,S,D)

  // QKV projections
  gemm_f32<<<dim3(32, 8), 256, 0, stream>>>(x, Wq, qws, 1024, 1024, 1024, 1024);
  gemm_f32<<<dim3(32, 2), 256, 0, stream>>>(x, Wk, kws, 1024, 1024, 256, 256);
  gemm_f32<<<dim3(32, 2), 256, 0, stream>>>(x, Wv, vws, 1024, 1024, 256, 256);
  // ve-gate, rope, rmsnorm
  postproc<<<dim3(4096), 256, 0, stream>>>(qws, kws, vws, x, ve, cosp, sinp, Wg);
  // sliding-window attention
  attn_swa<<<dim3(32, 16, 2), 256, 0, stream>>>(qws, kws, vws, yws, win);
  // output projection
  gemm_f32<<<dim3(32, 8), 256, 0, stream>>>(yws, Wo, out, 1024, 1024, 1024, 1024);
}

// Round 2
// 330.834 us; speedup vs baseline: 2.3074x; 2.3074x over previous
//
#include <hip/hip_runtime.h>
#include <hip/hip_bf16.h>
#include <cstddef>

// B=2, S=2048, D=1024, H=16, KVH=4, hd=64. window from d_in[9].

typedef short v8s __attribute__((ext_vector_type(8)));
typedef float v4f __attribute__((ext_vector_type(4)));

__device__ __forceinline__ ushort f2b(float f) {
  __hip_bfloat16 h = __float2bfloat16(f);
  return reinterpret_cast<ushort&>(h);
}

// ---------------- fp32 -> bf16 elementwise convert -------------------------
__global__ __launch_bounds__(256) void cvt_f32_bf16(
    const float* __restrict__ src, ushort* __restrict__ dst, int n)
{
  int i = (blockIdx.x * 256 + threadIdx.x) * 4;
  if (i >= n) return;
  float4 v = *(const float4*)(src + i);
  ushort4 o;
  o.x = f2b(v.x); o.y = f2b(v.y); o.z = f2b(v.z); o.w = f2b(v.w);
  *(ushort4*)(dst + i) = o;
}

// ---------------- fp32 [K][N] -> bf16 [N][K] transpose-convert -------------
// grid (N/32, K/32), 256 threads.
__global__ __launch_bounds__(256) void transpose_cvt(
    const float* __restrict__ W, ushort* __restrict__ Wt, int K, int N)
{
  __shared__ ushort tile[32][33];
  const int n0 = blockIdx.x * 32, k0 = blockIdx.y * 32;
  const int tx = threadIdx.x & 31, ty = threadIdx.x >> 5;  // ty in [0,8)
#pragma unroll
  for (int i = 0; i < 4; ++i) {
    const int k = ty + i * 8;
    tile[k][tx] = f2b(W[(size_t)(k0 + k) * N + n0 + tx]);
  }
  __syncthreads();
#pragma unroll
  for (int i = 0; i < 4; ++i) {
    const int n = ty + i * 8;
    Wt[(size_t)(n0 + n) * K + k0 + tx] = tile[tx][n];
  }
}

// ---------------- bf16 MFMA GEMM (NT): C[M,N] = A[M,K] . Bt[N,K]^T ---------
// 128x128 tile, BK=64, 256 threads = 4 waves, each wave 64x64 via 4x4 MFMA
// tiles of 16x16x32. M,N multiples of 128; K multiple of 64. fp32 out.
__device__ __forceinline__ void gemm_body(
    const ushort* __restrict__ A, const ushort* __restrict__ Bt,
    float* __restrict__ C, int N, int K, int m0, int n0)
{
  __shared__ ushort As[128][72];   // +8 bf16 pad: 2-way bank alias only
  __shared__ ushort Bs[128][72];
  const int t = threadIdx.x;
  const int lane = t & 63, wave = t >> 6;
  const int wr = wave >> 1, wc = wave & 1;
  const int quad = lane >> 4, l16 = lane & 15;

  v4f acc[4][4];
#pragma unroll
  for (int i = 0; i < 4; ++i)
#pragma unroll
    for (int j = 0; j < 4; ++j) acc[i][j] = (v4f){0.f, 0.f, 0.f, 0.f};

  const int row0 = t >> 3, oct = t & 7;   // 1024 chunks of 8 bf16, 4 per thread
  for (int k0 = 0; k0 < K; k0 += 64) {
#pragma unroll
    for (int i = 0; i < 4; ++i) {
      const int row = row0 + i * 32;
      *(int4*)&As[row][oct * 8] = *(const int4*)(A  + (size_t)(m0 + row) * K + k0 + oct * 8);
      *(int4*)&Bs[row][oct * 8] = *(const int4*)(Bt + (size_t)(n0 + row) * K + k0 + oct * 8);
    }
    __syncthreads();
#pragma unroll
    for (int ks = 0; ks < 2; ++ks) {
      v8s af[4], bf[4];
#pragma unroll
      for (int i = 0; i < 4; ++i) {
        af[i] = *(const v8s*)&As[wr * 64 + i * 16 + l16][ks * 32 + quad * 8];
        bf[i] = *(const v8s*)&Bs[wc * 64 + i * 16 + l16][ks * 32 + quad * 8];
      }
#pragma unroll
      for (int mt = 0; mt < 4; ++mt)
#pragma unroll
        for (int nt = 0; nt < 4; ++nt)
          acc[mt][nt] = __builtin_amdgcn_mfma_f32_16x16x32_bf16(
              af[mt], bf[nt], acc[mt][nt], 0, 0, 0);
    }
    __syncthreads();
  }
  // epilogue: D row = quad*4+reg, col = l16 (verified m89 mapping)
#pragma unroll
  for (int mt = 0; mt < 4; ++mt)
#pragma unroll
    for (int r = 0; r < 4; ++r) {
      float* cp = C + (size_t)(m0 + wr * 64 + mt * 16 + quad * 4 + r) * N
                    + n0 + wc * 64 + l16;
#pragma unroll
      for (int nt = 0; nt < 4; ++nt) cp[nt * 16] = acc[mt][nt][r];
    }
}

__global__ __launch_bounds__(256) void gemm_bf16nt(
    const ushort* __restrict__ A, const ushort* __restrict__ Bt,
    float* __restrict__ C, int N, int K)
{
  gemm_body(A, Bt, C, N, K, blockIdx.x * 128, blockIdx.y * 128);
}

// fused K/V projections: blockIdx.z picks weight/output
__global__ __launch_bounds__(256) void gemm_bf16nt_kv(
    const ushort* __restrict__ A, const ushort* __restrict__ Bt0,
    const ushort* __restrict__ Bt1, float* __restrict__ C0,
    float* __restrict__ C1, int N, int K)
{
  const ushort* Bt = blockIdx.z ? Bt1 : Bt0;
  float* C = blockIdx.z ? C1 : C0;
  gemm_body(A, Bt, C, N, K, blockIdx.x * 128, blockIdx.y * 128);
}

// ---------------- postprocess: ve-gate on V, rope+rmsnorm on Q,K -----------
__global__ __launch_bounds__(256) void postproc(
    float* __restrict__ qws, float* __restrict__ kws, float* __restrict__ vws,
    const float* __restrict__ x, const float* __restrict__ ve,
    const float* __restrict__ cosp, const float* __restrict__ sinp,
    const float* __restrict__ Wg)
{
  const int bs = blockIdx.x;
  const int s  = bs & 2047;
  const int t = threadIdx.x;
  const int wave = t >> 6, lane = t & 63;
  const int j = lane & 31;
  const float c  = cosp[s * 32 + j];
  const float sn = sinp[s * 32 + j];

  for (int task = wave; task < 24; task += 4) {
    if (task < 16) {
      const size_t base = (size_t)bs * 1024 + task * 64 + lane;
      float val = qws[base];
      float other = __shfl_xor(val, 32);
      float rot = (lane < 32) ? (val * c + other * sn) : (val * c - other * sn);
      float ss = rot * rot;
#pragma unroll
      for (int m = 1; m < 64; m <<= 1) ss += __shfl_xor(ss, m);
      float rs = rsqrtf(ss * (1.0f / 64.0f) + 1e-6f) * 1.2f;
      qws[base] = rot * rs;
    } else if (task < 20) {
      const int hk = task - 16;
      const size_t base = (size_t)bs * 256 + hk * 64 + lane;
      float val = kws[base];
      float other = __shfl_xor(val, 32);
      float rot = (lane < 32) ? (val * c + other * sn) : (val * c - other * sn);
      float ss = rot * rot;
#pragma unroll
      for (int m = 1; m < 64; m <<= 1) ss += __shfl_xor(ss, m);
      float rs = rsqrtf(ss * (1.0f / 64.0f) + 1e-6f) * 1.2f;
      kws[base] = rot * rs;
    } else {
      const int kvh = task - 20;
      float g = 0.f;
#pragma unroll
      for (int i = 0; i < 12; ++i) g += x[(size_t)bs * 1024 + i] * Wg[i * 4 + kvh];
      const float gate = 3.0f / (1.0f + __expf(-g));
      const size_t base = (size_t)bs * 256 + kvh * 64 + lane;
      vws[base] = vws[base] + gate * ve[base];
    }
  }
}

// ---------------- sliding-window causal GQA attention (fp32 flash) ---------
// Writes bf16 output for the Wo MFMA GEMM.
__global__ __launch_bounds__(256) void attn_swa(
    const float* __restrict__ qg, const float* __restrict__ kg,
    const float* __restrict__ vg, ushort* __restrict__ yb,
    const int* __restrict__ wptr)
{
  __shared__ float qs[64][68];
  __shared__ float kp[64][68];
  __shared__ float vs[64][68];
  const int qt = blockIdx.x, h = blockIdx.y, b = blockIdx.z;
  const int Wwin = *wptr;
  const int kvh = h >> 2;
  const int q0 = qt * 64;
  const int t = threadIdx.x, tx = t & 15, ty = t >> 4;

  for (int u = t; u < 1024; u += 256) {
    const int row = u >> 4, c4 = u & 15;
    float4 qv = *(const float4*)(qg + ((size_t)(b * 2048 + q0 + row)) * 1024 + h * 64 + c4 * 4);
    qs[c4 * 4 + 0][row] = qv.x; qs[c4 * 4 + 1][row] = qv.y;
    qs[c4 * 4 + 2][row] = qv.z; qs[c4 * 4 + 3][row] = qv.w;
  }

  float m_r[4], l_r[4], acc[4][4];
#pragma unroll
  for (int r = 0; r < 4; ++r) {
    m_r[r] = -1e30f; l_r[r] = 0.f;
#pragma unroll
    for (int c = 0; c < 4; ++c) acc[r][c] = 0.f;
  }

  const int kt0 = (qt >= 8) ? (qt - 8) : 0;
  for (int kt = kt0; kt <= qt; ++kt) {
    for (int u = t; u < 1024; u += 256) {
      const int row = u >> 4, c4 = u & 15;
      const size_t gb = ((size_t)(b * 2048 + kt * 64 + row)) * 256 + kvh * 64 + c4 * 4;
      float4 kv = *(const float4*)(kg + gb);
      float4 vv = *(const float4*)(vg + gb);
      kp[c4 * 4 + 0][row] = kv.x; kp[c4 * 4 + 1][row] = kv.y;
      kp[c4 * 4 + 2][row] = kv.z; kp[c4 * 4 + 3][row] = kv.w;
      *(float4*)&vs[row][c4 * 4] = vv;
    }
    __syncthreads();

    float s[4][4];
#pragma unroll
    for (int r = 0; r < 4; ++r)
#pragma unroll
      for (int c = 0; c < 4; ++c) s[r][c] = 0.f;
#pragma unroll 8
    for (int d = 0; d < 64; ++d) {
      float4 qv = *(const float4*)&qs[d][ty * 4];
      float4 kv = *(const float4*)&kp[d][tx * 4];
      float qr[4] = {qv.x, qv.y, qv.z, qv.w};
      float kr[4] = {kv.x, kv.y, kv.z, kv.w};
#pragma unroll
      for (int r = 0; r < 4; ++r)
#pragma unroll
        for (int c = 0; c < 4; ++c) s[r][c] += qr[r] * kr[c];
    }
    __syncthreads();

#pragma unroll
    for (int r = 0; r < 4; ++r) {
      const int qrow = q0 + ty * 4 + r;
      float sv[4];
#pragma unroll
      for (int c = 0; c < 4; ++c) {
        const int kcol = kt * 64 + tx * 4 + c;
        const bool ok = (kcol <= qrow) && (kcol > qrow - Wwin);
        sv[c] = ok ? s[r][c] * 0.125f : -1e30f;
      }
      float mt = fmaxf(fmaxf(sv[0], sv[1]), fmaxf(sv[2], sv[3]));
      mt = fmaxf(mt, __shfl_xor(mt, 1));
      mt = fmaxf(mt, __shfl_xor(mt, 2));
      mt = fmaxf(mt, __shfl_xor(mt, 4));
      mt = fmaxf(mt, __shfl_xor(mt, 8));
      const float mn = fmaxf(m_r[r], mt);
      const float al = __expf(m_r[r] - mn);
      float psum = 0.f;
#pragma unroll
      for (int c = 0; c < 4; ++c) {
        const float p = __expf(sv[c] - mn);
        kp[ty * 4 + r][tx * 4 + c] = p;
        psum += p;
      }
      psum += __shfl_xor(psum, 1);
      psum += __shfl_xor(psum, 2);
      psum += __shfl_xor(psum, 4);
      psum += __shfl_xor(psum, 8);
      l_r[r] = l_r[r] * al + psum;
      m_r[r] = mn;
#pragma unroll
      for (int c = 0; c < 4; ++c) acc[r][c] *= al;
    }
    __syncthreads();

#pragma unroll 4
    for (int k4 = 0; k4 < 16; ++k4) {
      float pr[4][4], vr[4][4];
#pragma unroll
      for (int r = 0; r < 4; ++r) {
        float4 pv = *(const float4*)&kp[ty * 4 + r][k4 * 4];
        pr[r][0] = pv.x; pr[r][1] = pv.y; pr[r][2] = pv.z; pr[r][3] = pv.w;
      }
#pragma unroll
      for (int jj = 0; jj < 4; ++jj) {
        float4 vv = *(const float4*)&vs[k4 * 4 + jj][tx * 4];
        vr[jj][0] = vv.x; vr[jj][1] = vv.y; vr[jj][2] = vv.z; vr[jj][3] = vv.w;
      }
#pragma unroll
      for (int r = 0; r < 4; ++r)
#pragma unroll
        for (int jj = 0; jj < 4; ++jj)
#pragma unroll
          for (int c = 0; c < 4; ++c) acc[r][c] += pr[r][jj] * vr[jj][c];
    }
    __syncthreads();
  }

#pragma unroll
  for (int r = 0; r < 4; ++r) {
    const float inv = 1.0f / l_r[r];
    uint lo = (uint)f2b(acc[r][0] * inv) | ((uint)f2b(acc[r][1] * inv) << 16);
    uint hi = (uint)f2b(acc[r][2] * inv) | ((uint)f2b(acc[r][3] * inv) << 16);
    *(uint2*)(yb + ((size_t)(b * 2048 + q0 + ty * 4 + r)) * 1024 + h * 64 + tx * 4) =
        make_uint2(lo, hi);
  }
}

// ---------------------------------------------------------------------------
extern "C" void kernel_launch(void* const* d_in, const int* in_sizes, int n_in,
                              void* d_out, int out_size, void* d_ws, size_t ws_size,
                              hipStream_t stream)
{
  const float* x    = (const float*)d_in[0];
  const float* ve   = (const float*)d_in[1];
  const float* cosp = (const float*)d_in[2];
  const float* sinp = (const float*)d_in[3];
  const float* Wq   = (const float*)d_in[4];
  const float* Wk   = (const float*)d_in[5];
  const float* Wv   = (const float*)d_in[6];
  const float* Wo   = (const float*)d_in[7];
  const float* Wg   = (const float*)d_in[8];
  const int*   win  = (const int*)d_in[9];
  float* out = (float*)d_out;

  char* p = (char*)d_ws;
  float*  qws = (float*)p;                 p += 4194304 * 4;   // 16 MB
  float*  kws = (float*)p;                 p += 1048576 * 4;   //  4 MB
  float*  vws = (float*)p;                 p += 1048576 * 4;   //  4 MB
  ushort* xb  = (ushort*)p;                p += 4194304 * 2;   //  8 MB
  ushort* yb  = (ushort*)p;                p += 4194304 * 2;   //  8 MB
  ushort* Wqt = (ushort*)p;                p += 1048576 * 2;   //  2 MB
  ushort* Wot = (ushort*)p;                p += 1048576 * 2;   //  2 MB
  ushort* Wkt = (ushort*)p;                p +=  262144 * 2;   // .5 MB
  ushort* Wvt = (ushort*)p;                                     // .5 MB

  // converts / transposes
  cvt_f32_bf16<<<4096, 256, 0, stream>>>(x, xb, 4194304);
  transpose_cvt<<<dim3(32, 32), 256, 0, stream>>>(Wq, Wqt, 1024, 1024);
  transpose_cvt<<<dim3(8, 32), 256, 0, stream>>>(Wk, Wkt, 1024, 256);
  transpose_cvt<<<dim3(8, 32), 256, 0, stream>>>(Wv, Wvt, 1024, 256);
  transpose_cvt<<<dim3(32, 32), 256, 0, stream>>>(Wo, Wot, 1024, 1024);

  // projections (bf16 MFMA)
  gemm_bf16nt<<<dim3(32, 8), 256, 0, stream>>>(xb, Wqt, qws, 1024, 1024);
  gemm_bf16nt_kv<<<dim3(32, 2, 2), 256, 0, stream>>>(xb, Wkt, Wvt, kws, vws, 256, 1024);

  // ve-gate, rope, rmsnorm (fp32)
  postproc<<<dim3(4096), 256, 0, stream>>>(qws, kws, vws, x, ve, cosp, sinp, Wg);

  // attention (fp32, bf16 out)
  attn_swa<<<dim3(32, 16, 2), 256, 0, stream>>>(qws, kws, vws, yb, win);

  // output projection (bf16 MFMA)
  gemm_bf16nt<<<dim3(32, 8), 256, 0, stream>>>(yb, Wot, out, 1024, 1024);
}

// Round 3
// 211.942 us; speedup vs baseline: 3.6018x; 1.5610x over previous
//
#include <hip/hip_runtime.h>
#include <hip/hip_bf16.h>
#include <cstddef>

// B=2, S=2048, D=1024, H=16, KVH=4, hd=64. window from d_in[9].

typedef short v8s __attribute__((ext_vector_type(8)));
typedef float v4f __attribute__((ext_vector_type(4)));

__device__ __forceinline__ ushort f2b(float f) {
  __hip_bfloat16 h = __float2bfloat16(f);
  return reinterpret_cast<ushort&>(h);
}

// ---------------- fp32 -> bf16 elementwise convert -------------------------
__global__ __launch_bounds__(256) void cvt_f32_bf16(
    const float* __restrict__ src, ushort* __restrict__ dst, int n)
{
  int i = (blockIdx.x * 256 + threadIdx.x) * 4;
  if (i >= n) return;
  float4 v = *(const float4*)(src + i);
  ushort4 o;
  o.x = f2b(v.x); o.y = f2b(v.y); o.z = f2b(v.z); o.w = f2b(v.w);
  *(ushort4*)(dst + i) = o;
}

// ---------------- 4 weight transposes fused: fp32 [K][N] -> bf16 [N][K] ----
__global__ __launch_bounds__(256) void transpose_cvt4(
    const float* __restrict__ Wq, const float* __restrict__ Wk,
    const float* __restrict__ Wv, const float* __restrict__ Wo,
    ushort* __restrict__ Wqt, ushort* __restrict__ Wkt,
    ushort* __restrict__ Wvt, ushort* __restrict__ Wot)
{
  __shared__ ushort tile[32][33];
  const int z = blockIdx.z;
  const float* W = (z == 0) ? Wq : (z == 1) ? Wo : (z == 2) ? Wk : Wv;
  ushort* Wt     = (z == 0) ? Wqt : (z == 1) ? Wot : (z == 2) ? Wkt : Wvt;
  const int N = (z < 2) ? 1024 : 256;
  const int n0 = blockIdx.x * 32, k0 = blockIdx.y * 32;
  if (n0 >= N) return;
  const int tx = threadIdx.x & 31, ty = threadIdx.x >> 5;
#pragma unroll
  for (int i = 0; i < 4; ++i) {
    const int k = ty + i * 8;
    tile[k][tx] = f2b(W[(size_t)(k0 + k) * N + n0 + tx]);
  }
  __syncthreads();
#pragma unroll
  for (int i = 0; i < 4; ++i) {
    const int n = ty + i * 8;
    Wt[(size_t)(n0 + n) * 1024 + k0 + tx] = tile[tx][n];
  }
}

// ---------------- bf16 MFMA GEMM (NT): C[M,N] = A[M,K] . Bt[N,K]^T ---------
__device__ __forceinline__ void gemm_body(
    const ushort* __restrict__ A, const ushort* __restrict__ Bt,
    float* __restrict__ C, int N, int K, int m0, int n0)
{
  __shared__ ushort As[128][72];
  __shared__ ushort Bs[128][72];
  const int t = threadIdx.x;
  const int lane = t & 63, wave = t >> 6;
  const int wr = wave >> 1, wc = wave & 1;
  const int quad = lane >> 4, l16 = lane & 15;

  v4f acc[4][4];
#pragma unroll
  for (int i = 0; i < 4; ++i)
#pragma unroll
    for (int j = 0; j < 4; ++j) acc[i][j] = (v4f){0.f, 0.f, 0.f, 0.f};

  const int row0 = t >> 3, oct = t & 7;
  for (int k0 = 0; k0 < K; k0 += 64) {
#pragma unroll
    for (int i = 0; i < 4; ++i) {
      const int row = row0 + i * 32;
      *(int4*)&As[row][oct * 8] = *(const int4*)(A  + (size_t)(m0 + row) * K + k0 + oct * 8);
      *(int4*)&Bs[row][oct * 8] = *(const int4*)(Bt + (size_t)(n0 + row) * K + k0 + oct * 8);
    }
    __syncthreads();
#pragma unroll
    for (int ks = 0; ks < 2; ++ks) {
      v8s af[4], bf[4];
#pragma unroll
      for (int i = 0; i < 4; ++i) {
        af[i] = *(const v8s*)&As[wr * 64 + i * 16 + l16][ks * 32 + quad * 8];
        bf[i] = *(const v8s*)&Bs[wc * 64 + i * 16 + l16][ks * 32 + quad * 8];
      }
#pragma unroll
      for (int mt = 0; mt < 4; ++mt)
#pragma unroll
        for (int nt = 0; nt < 4; ++nt)
          acc[mt][nt] = __builtin_amdgcn_mfma_f32_16x16x32_bf16(
              af[mt], bf[nt], acc[mt][nt], 0, 0, 0);
    }
    __syncthreads();
  }
#pragma unroll
  for (int mt = 0; mt < 4; ++mt)
#pragma unroll
    for (int r = 0; r < 4; ++r) {
      float* cp = C + (size_t)(m0 + wr * 64 + mt * 16 + quad * 4 + r) * N
                    + n0 + wc * 64 + l16;
#pragma unroll
      for (int nt = 0; nt < 4; ++nt) cp[nt * 16] = acc[mt][nt][r];
    }
}

__global__ __launch_bounds__(256) void gemm_bf16nt(
    const ushort* __restrict__ A, const ushort* __restrict__ Bt,
    float* __restrict__ C, int N, int K)
{
  gemm_body(A, Bt, C, N, K, blockIdx.x * 128, blockIdx.y * 128);
}

__global__ __launch_bounds__(256) void gemm_bf16nt_kv(
    const ushort* __restrict__ A, const ushort* __restrict__ Bt0,
    const ushort* __restrict__ Bt1, float* __restrict__ C0,
    float* __restrict__ C1, int N, int K)
{
  const ushort* Bt = blockIdx.z ? Bt1 : Bt0;
  float* C = blockIdx.z ? C1 : C0;
  gemm_body(A, Bt, C, N, K, blockIdx.x * 128, blockIdx.y * 128);
}

// ---------------- postprocess: emits bf16 qb, kb and transposed vtb --------
// vtb layout: [b][kvh][d=64][s=2048] bf16 (for coalesced Vt staging in attn).
__global__ __launch_bounds__(256) void postproc(
    const float* __restrict__ qws, const float* __restrict__ kws,
    const float* __restrict__ vws, const float* __restrict__ x,
    const float* __restrict__ ve, const float* __restrict__ cosp,
    const float* __restrict__ sinp, const float* __restrict__ Wg,
    ushort* __restrict__ qb, ushort* __restrict__ kb, ushort* __restrict__ vtb)
{
  const int bs = blockIdx.x;
  const int s = bs & 2047, b = bs >> 11;
  const int t = threadIdx.x;
  const int wave = t >> 6, lane = t & 63;
  const int j = lane & 31;
  const float c  = cosp[s * 32 + j];
  const float sn = sinp[s * 32 + j];

  for (int task = wave; task < 24; task += 4) {
    if (task < 16) {
      const size_t base = (size_t)bs * 1024 + task * 64 + lane;
      float val = qws[base];
      float other = __shfl_xor(val, 32);
      float rot = (lane < 32) ? (val * c + other * sn) : (val * c - other * sn);
      float ss = rot * rot;
#pragma unroll
      for (int m = 1; m < 64; m <<= 1) ss += __shfl_xor(ss, m);
      float rs = rsqrtf(ss * (1.0f / 64.0f) + 1e-6f) * 1.2f;
      qb[base] = f2b(rot * rs);
    } else if (task < 20) {
      const int hk = task - 16;
      const size_t base = (size_t)bs * 256 + hk * 64 + lane;
      float val = kws[base];
      float other = __shfl_xor(val, 32);
      float rot = (lane < 32) ? (val * c + other * sn) : (val * c - other * sn);
      float ss = rot * rot;
#pragma unroll
      for (int m = 1; m < 64; m <<= 1) ss += __shfl_xor(ss, m);
      float rs = rsqrtf(ss * (1.0f / 64.0f) + 1e-6f) * 1.2f;
      kb[base] = f2b(rot * rs);
    } else {
      const int kvh = task - 20;
      float g = 0.f;
#pragma unroll
      for (int i = 0; i < 12; ++i) g += x[(size_t)bs * 1024 + i] * Wg[i * 4 + kvh];
      const float gate = 3.0f / (1.0f + __expf(-g));
      const size_t base = (size_t)bs * 256 + kvh * 64 + lane;
      const float v = vws[base] + gate * ve[base];
      vtb[((size_t)((b * 4 + kvh) * 64 + lane)) * 2048 + s] = f2b(v);
    }
  }
}

// ---------------- MFMA flash attention (sliding-window causal GQA) ---------
// grid (S/64, H, B), 256 threads = 4 waves; wave = 16-q-row strip.
__global__ __launch_bounds__(256) void attn_mfma(
    const ushort* __restrict__ qb, const ushort* __restrict__ kb,
    const ushort* __restrict__ vtb, ushort* __restrict__ yb,
    const int* __restrict__ wptr)
{
  __shared__ ushort Ks[64][72];   // K tile  [k][d]
  __shared__ ushort Vt[64][72];   // V tile  [d][k]
  __shared__ ushort Ps[64][72];   // P tile  [q][k] (bf16, per-wave strips)
  const int qt = blockIdx.x, h = blockIdx.y, b = blockIdx.z;
  const int kvh = h >> 2, q0 = qt * 64;
  const int t = threadIdx.x, lane = t & 63, wave = t >> 6;
  const int quad = lane >> 4, l16 = lane & 15;
  const int Wwin = *wptr;

  // Q fragments held in registers: A[m=l16][k-contig], rows q0+wave*16+l16
  v8s qf0, qf1;
  {
    const ushort* qp = qb + ((size_t)(b * 2048 + q0 + wave * 16 + l16)) * 1024
                          + h * 64 + quad * 8;
    qf0 = *(const v8s*)qp;
    qf1 = *(const v8s*)(qp + 32);
  }

  v4f o[4];
  float m_r[4], l_r[4];
#pragma unroll
  for (int i = 0; i < 4; ++i) o[i] = (v4f){0.f, 0.f, 0.f, 0.f};
#pragma unroll
  for (int r = 0; r < 4; ++r) { m_r[r] = -1e30f; l_r[r] = 0.f; }

  const int lo = q0 - Wwin + 1;
  const int kt0 = (lo > 0) ? (lo >> 6) : 0;

  for (int kt = kt0; kt <= qt; ++kt) {
    // ---- stage K [k][d] and Vt [d][k] (both coalesced int4) ----
#pragma unroll
    for (int i = 0; i < 2; ++i) {
      const int cc = t + i * 256;            // 0..511
      const int r8 = cc >> 3, c8 = (cc & 7) * 8;
      *(int4*)&Ks[r8][c8] =
          *(const int4*)(kb + ((size_t)(b * 2048 + kt * 64 + r8)) * 256 + kvh * 64 + c8);
      *(int4*)&Vt[r8][c8] =
          *(const int4*)(vtb + ((size_t)((b * 4 + kvh) * 64 + r8)) * 2048 + kt * 64 + c8);
    }
    __syncthreads();

    // ---- S = Q K^T : 4 col-tiles of 16, K=64 in 2 mfma ----
    v4f s[4];
#pragma unroll
    for (int n = 0; n < 4; ++n) {
      s[n] = (v4f){0.f, 0.f, 0.f, 0.f};
      v8s kf0 = *(const v8s*)&Ks[n * 16 + l16][quad * 8];
      v8s kf1 = *(const v8s*)&Ks[n * 16 + l16][32 + quad * 8];
      s[n] = __builtin_amdgcn_mfma_f32_16x16x32_bf16(qf0, kf0, s[n], 0, 0, 0);
      s[n] = __builtin_amdgcn_mfma_f32_16x16x32_bf16(qf1, kf1, s[n], 0, 0, 0);
    }

    // ---- mask + online softmax (C layout: row=quad*4+r, col=l16) ----
    const int qrow = q0 + wave * 16 + quad * 4;
    const int kbase = kt * 64 + l16;
    float sv[4][4], mt[4];
#pragma unroll
    for (int r = 0; r < 4; ++r) mt[r] = -1e30f;
#pragma unroll
    for (int n = 0; n < 4; ++n)
#pragma unroll
      for (int r = 0; r < 4; ++r) {
        const int k = kbase + n * 16, q = qrow + r;
        const bool ok = (k <= q) && (k > q - Wwin);
        const float v = ok ? s[n][r] * 0.125f : -1e30f;
        sv[n][r] = v;
        mt[r] = fmaxf(mt[r], v);
      }
#pragma unroll
    for (int r = 0; r < 4; ++r) {
      mt[r] = fmaxf(mt[r], __shfl_xor(mt[r], 1));
      mt[r] = fmaxf(mt[r], __shfl_xor(mt[r], 2));
      mt[r] = fmaxf(mt[r], __shfl_xor(mt[r], 4));
      mt[r] = fmaxf(mt[r], __shfl_xor(mt[r], 8));
    }
    float al[4], ps[4];
#pragma unroll
    for (int r = 0; r < 4; ++r) {
      const float mn = fmaxf(m_r[r], mt[r]);
      al[r] = __expf(m_r[r] - mn);   // exp(0)=1 when both -1e30: self-heals
      m_r[r] = mn;
      ps[r] = 0.f;
    }
#pragma unroll
    for (int n = 0; n < 4; ++n)
#pragma unroll
      for (int r = 0; r < 4; ++r) {
        const float p = __expf(sv[n][r] - m_r[r]);
        ps[r] += p;
        Ps[wave * 16 + quad * 4 + r][n * 16 + l16] = f2b(p);
      }
#pragma unroll
    for (int r = 0; r < 4; ++r) {
      ps[r] += __shfl_xor(ps[r], 1);
      ps[r] += __shfl_xor(ps[r], 2);
      ps[r] += __shfl_xor(ps[r], 4);
      ps[r] += __shfl_xor(ps[r], 8);
      l_r[r] = l_r[r] * al[r] + ps[r];
#pragma unroll
      for (int dt = 0; dt < 4; ++dt) o[dt][r] *= al[r];
    }

    // ---- O += P V  (P strip is wave-private; no barrier needed) ----
    v8s pf0 = *(const v8s*)&Ps[wave * 16 + l16][quad * 8];
    v8s pf1 = *(const v8s*)&Ps[wave * 16 + l16][32 + quad * 8];
#pragma unroll
    for (int dt = 0; dt < 4; ++dt) {
      v8s vf0 = *(const v8s*)&Vt[dt * 16 + l16][quad * 8];
      v8s vf1 = *(const v8s*)&Vt[dt * 16 + l16][32 + quad * 8];
      o[dt] = __builtin_amdgcn_mfma_f32_16x16x32_bf16(pf0, vf0, o[dt], 0, 0, 0);
      o[dt] = __builtin_amdgcn_mfma_f32_16x16x32_bf16(pf1, vf1, o[dt], 0, 0, 0);
    }
    __syncthreads();   // protect Ks/Vt before next staging
  }

  // ---- epilogue: O/l -> bf16 yb ----
#pragma unroll
  for (int r = 0; r < 4; ++r) {
    const float inv = 1.0f / l_r[r];
    ushort* yp = yb + ((size_t)(b * 2048 + q0 + wave * 16 + quad * 4 + r)) * 1024
                    + h * 64 + l16;
#pragma unroll
    for (int dt = 0; dt < 4; ++dt) yp[dt * 16] = f2b(o[dt][r] * inv);
  }
}

// ---------------------------------------------------------------------------
extern "C" void kernel_launch(void* const* d_in, const int* in_sizes, int n_in,
                              void* d_out, int out_size, void* d_ws, size_t ws_size,
                              hipStream_t stream)
{
  const float* x    = (const float*)d_in[0];
  const float* ve   = (const float*)d_in[1];
  const float* cosp = (const float*)d_in[2];
  const float* sinp = (const float*)d_in[3];
  const float* Wq   = (const float*)d_in[4];
  const float* Wk   = (const float*)d_in[5];
  const float* Wv   = (const float*)d_in[6];
  const float* Wo   = (const float*)d_in[7];
  const float* Wg   = (const float*)d_in[8];
  const int*   win  = (const int*)d_in[9];
  float* out = (float*)d_out;

  char* p = (char*)d_ws;
  float*  qws = (float*)p;   p += 4194304 * 4;   // 16 MB (later reused as yb)
  float*  kws = (float*)p;   p += 1048576 * 4;   //  4 MB
  float*  vws = (float*)p;   p += 1048576 * 4;   //  4 MB
  ushort* xb  = (ushort*)p;  p += 4194304 * 2;   //  8 MB (later reused as qb)
  ushort* kb  = (ushort*)p;  p += 1048576 * 2;   //  2 MB
  ushort* vtb = (ushort*)p;  p += 1048576 * 2;   //  2 MB
  ushort* Wqt = (ushort*)p;  p += 1048576 * 2;   //  2 MB
  ushort* Wot = (ushort*)p;  p += 1048576 * 2;   //  2 MB
  ushort* Wkt = (ushort*)p;  p +=  262144 * 2;   // .5 MB
  ushort* Wvt = (ushort*)p;                      // .5 MB
  ushort* qb  = xb;             // alias: xb free after KV gemm
  ushort* yb  = (ushort*)qws;   // alias: qws free after postproc

  cvt_f32_bf16<<<4096, 256, 0, stream>>>(x, xb, 4194304);
  transpose_cvt4<<<dim3(32, 32, 4), 256, 0, stream>>>(Wq, Wk, Wv, Wo, Wqt, Wkt, Wvt, Wot);

  gemm_bf16nt<<<dim3(32, 8), 256, 0, stream>>>(xb, Wqt, qws, 1024, 1024);
  gemm_bf16nt_kv<<<dim3(32, 2, 2), 256, 0, stream>>>(xb, Wkt, Wvt, kws, vws, 256, 1024);

  postproc<<<dim3(4096), 256, 0, stream>>>(qws, kws, vws, x, ve, cosp, sinp, Wg,
                                           qb, kb, vtb);

  attn_mfma<<<dim3(32, 16, 2), 256, 0, stream>>>(qb, kb, vtb, yb, win);

  gemm_bf16nt<<<dim3(32, 8), 256, 0, stream>>>(yb, Wot, out, 1024, 1024);
}

// Round 4
// 188.521 us; speedup vs baseline: 4.0493x; 1.1242x over previous
//
#include <hip/hip_runtime.h>
#include <hip/hip_bf16.h>
#include <cstddef>

// B=2, S=2048, D=1024, H=16, KVH=4, hd=64. window from d_in[9].

typedef short v8s __attribute__((ext_vector_type(8)));
typedef float v4f __attribute__((ext_vector_type(4)));

__device__ __forceinline__ ushort f2b(float f) {
  __hip_bfloat16 h = __float2bfloat16(f);
  return reinterpret_cast<ushort&>(h);
}

// ---------------- fp32 -> bf16 elementwise convert -------------------------
__global__ __launch_bounds__(256) void cvt_f32_bf16(
    const float* __restrict__ src, ushort* __restrict__ dst, int n)
{
  int i = (blockIdx.x * 256 + threadIdx.x) * 4;
  if (i >= n) return;
  float4 v = *(const float4*)(src + i);
  ushort4 o;
  o.x = f2b(v.x); o.y = f2b(v.y); o.z = f2b(v.z); o.w = f2b(v.w);
  *(ushort4*)(dst + i) = o;
}

// ---------------- 4 weight transposes fused: fp32 [K][N] -> bf16 [N][K] ----
// Wq/Wk/Wv write into one concatenated [1536][1024] buffer (via base ptrs).
__global__ __launch_bounds__(256) void transpose_cvt4(
    const float* __restrict__ Wq, const float* __restrict__ Wk,
    const float* __restrict__ Wv, const float* __restrict__ Wo,
    ushort* __restrict__ Wqt, ushort* __restrict__ Wkt,
    ushort* __restrict__ Wvt, ushort* __restrict__ Wot)
{
  __shared__ ushort tile[32][33];
  const int z = blockIdx.z;
  const float* W = (z == 0) ? Wq : (z == 1) ? Wo : (z == 2) ? Wk : Wv;
  ushort* Wt     = (z == 0) ? Wqt : (z == 1) ? Wot : (z == 2) ? Wkt : Wvt;
  const int N = (z < 2) ? 1024 : 256;
  const int n0 = blockIdx.x * 32, k0 = blockIdx.y * 32;
  if (n0 >= N) return;
  const int tx = threadIdx.x & 31, ty = threadIdx.x >> 5;
#pragma unroll
  for (int i = 0; i < 4; ++i) {
    const int k = ty + i * 8;
    tile[k][tx] = f2b(W[(size_t)(k0 + k) * N + n0 + tx]);
  }
  __syncthreads();
#pragma unroll
  for (int i = 0; i < 4; ++i) {
    const int n = ty + i * 8;
    Wt[(size_t)(n0 + n) * 1024 + k0 + tx] = tile[tx][n];
  }
}

// ---------------- bf16 MFMA GEMM (NT): C[M,N] = A[M,K] . Bt[N,K]^T ---------
__global__ __launch_bounds__(256) void gemm_bf16nt(
    const ushort* __restrict__ A, const ushort* __restrict__ Bt,
    float* __restrict__ C, int N, int K)
{
  __shared__ ushort As[128][72];
  __shared__ ushort Bs[128][72];
  const int m0 = blockIdx.x * 128, n0 = blockIdx.y * 128;
  const int t = threadIdx.x;
  const int lane = t & 63, wave = t >> 6;
  const int wr = wave >> 1, wc = wave & 1;
  const int quad = lane >> 4, l16 = lane & 15;

  v4f acc[4][4];
#pragma unroll
  for (int i = 0; i < 4; ++i)
#pragma unroll
    for (int j = 0; j < 4; ++j) acc[i][j] = (v4f){0.f, 0.f, 0.f, 0.f};

  const int row0 = t >> 3, oct = t & 7;
  for (int k0 = 0; k0 < K; k0 += 64) {
#pragma unroll
    for (int i = 0; i < 4; ++i) {
      const int row = row0 + i * 32;
      *(int4*)&As[row][oct * 8] = *(const int4*)(A  + (size_t)(m0 + row) * K + k0 + oct * 8);
      *(int4*)&Bs[row][oct * 8] = *(const int4*)(Bt + (size_t)(n0 + row) * K + k0 + oct * 8);
    }
    __syncthreads();
#pragma unroll
    for (int ks = 0; ks < 2; ++ks) {
      v8s af[4], bf[4];
#pragma unroll
      for (int i = 0; i < 4; ++i) {
        af[i] = *(const v8s*)&As[wr * 64 + i * 16 + l16][ks * 32 + quad * 8];
        bf[i] = *(const v8s*)&Bs[wc * 64 + i * 16 + l16][ks * 32 + quad * 8];
      }
#pragma unroll
      for (int mt = 0; mt < 4; ++mt)
#pragma unroll
        for (int nt = 0; nt < 4; ++nt)
          acc[mt][nt] = __builtin_amdgcn_mfma_f32_16x16x32_bf16(
              af[mt], bf[nt], acc[mt][nt], 0, 0, 0);
    }
    __syncthreads();
  }
#pragma unroll
  for (int mt = 0; mt < 4; ++mt)
#pragma unroll
    for (int r = 0; r < 4; ++r) {
      float* cp = C + (size_t)(m0 + wr * 64 + mt * 16 + quad * 4 + r) * N
                    + n0 + wc * 64 + l16;
#pragma unroll
      for (int nt = 0; nt < 4; ++nt) cp[nt * 16] = acc[mt][nt][r];
    }
}

// ---------------- postprocess: reads fused qkv fp32 [4096][1536] -----------
// emits bf16 qb [bs][h*64+d], kb [bs][kvh*64+d], vtb [b][kvh][d][s].
__global__ __launch_bounds__(256) void postproc(
    const float* __restrict__ qkv, const float* __restrict__ x,
    const float* __restrict__ ve, const float* __restrict__ cosp,
    const float* __restrict__ sinp, const float* __restrict__ Wg,
    ushort* __restrict__ qb, ushort* __restrict__ kb, ushort* __restrict__ vtb)
{
  const int bs = blockIdx.x;
  const int s = bs & 2047, b = bs >> 11;
  const int t = threadIdx.x;
  const int wave = t >> 6, lane = t & 63;
  const int j = lane & 31;
  const float c  = cosp[s * 32 + j];
  const float sn = sinp[s * 32 + j];
  const float* row = qkv + (size_t)bs * 1536;

  for (int task = wave; task < 24; task += 4) {
    if (task < 16) {
      float val = row[task * 64 + lane];
      float other = __shfl_xor(val, 32);
      float rot = (lane < 32) ? (val * c + other * sn) : (val * c - other * sn);
      float ss = rot * rot;
#pragma unroll
      for (int m = 1; m < 64; m <<= 1) ss += __shfl_xor(ss, m);
      float rs = rsqrtf(ss * (1.0f / 64.0f) + 1e-6f) * 1.2f;
      qb[(size_t)bs * 1024 + task * 64 + lane] = f2b(rot * rs);
    } else if (task < 20) {
      const int hk = task - 16;
      float val = row[1024 + hk * 64 + lane];
      float other = __shfl_xor(val, 32);
      float rot = (lane < 32) ? (val * c + other * sn) : (val * c - other * sn);
      float ss = rot * rot;
#pragma unroll
      for (int m = 1; m < 64; m <<= 1) ss += __shfl_xor(ss, m);
      float rs = rsqrtf(ss * (1.0f / 64.0f) + 1e-6f) * 1.2f;
      kb[(size_t)bs * 256 + hk * 64 + lane] = f2b(rot * rs);
    } else {
      const int kvh = task - 20;
      float g = 0.f;
#pragma unroll
      for (int i = 0; i < 12; ++i) g += x[(size_t)bs * 1024 + i] * Wg[i * 4 + kvh];
      const float gate = 3.0f / (1.0f + __expf(-g));
      const float v = row[1280 + kvh * 64 + lane] + gate * ve[(size_t)bs * 256 + kvh * 64 + lane];
      vtb[((size_t)((b * 4 + kvh) * 64 + lane)) * 2048 + s] = f2b(v);
    }
  }
}

// ---------------- MFMA flash attention, fixed-max softmax ------------------
// Scores bounded: |q.k|*0.125 <= (1.2*8)^2*0.125 = 11.52 (+bf16 eps) < 12,
// so p = exp(s*0.125 - 12) needs NO online max / rescale. Row-sum l comes
// from a ones-row appended to V (d-tile 4). S computed TRANSPOSED
// (mfma(K,Q)) so P exits in [q=l16][k contiguous] layout: b64 LDS writes and
// direct A-fragment reads for PV. Block = 128 q-rows (2 strips/wave).
__global__ __launch_bounds__(256) void attn_mfma(
    const ushort* __restrict__ qb, const ushort* __restrict__ kb,
    const ushort* __restrict__ vtb, ushort* __restrict__ yb,
    const int* __restrict__ wptr)
{
  __shared__ ushort Ks[64][72];    // K tile  [k][d]
  __shared__ ushort Vt[80][72];    // V^T tile [d][k]; rows 64..79 = ones-row block
  __shared__ ushort Ps[128][72];   // P [q][k], wave-private 32-row strips
  const int qt = blockIdx.x, h = blockIdx.y, b = blockIdx.z;
  const int kvh = h >> 2, q0 = qt * 128;
  const int t = threadIdx.x, lane = t & 63, wave = t >> 6;
  const int quad = lane >> 4, l16 = lane & 15;
  const int Wwin = *wptr;

  // Q fragments (2 strips of 16 rows per wave), held in registers
  v8s qf[2][2];
#pragma unroll
  for (int s = 0; s < 2; ++s) {
    const ushort* qp = qb + ((size_t)(b * 2048 + q0 + wave * 32 + s * 16 + l16)) * 1024
                          + h * 64 + quad * 8;
    qf[s][0] = *(const v8s*)qp;
    qf[s][1] = *(const v8s*)(qp + 32);
  }

  // ones-row block for l accumulation: Vt[64][*] = 1.0bf16, Vt[65..79][*] = 0
  if (t < 128) {
    const int row = 64 + (t >> 3), c8 = (t & 7) * 8;
    const int v = (row == 64) ? 0x3F803F80 : 0;
    int4 w; w.x = v; w.y = v; w.z = v; w.w = v;
    *(int4*)&Vt[row][c8] = w;
  }

  v4f o[2][5];
#pragma unroll
  for (int s = 0; s < 2; ++s)
#pragma unroll
    for (int d = 0; d < 5; ++d) o[s][d] = (v4f){0.f, 0.f, 0.f, 0.f};

  const int lo = q0 - Wwin + 1;
  const int kt0 = (lo > 0) ? (lo >> 6) : 0;
  const int kt1 = (q0 + 127) >> 6;

  for (int kt = kt0; kt <= kt1; ++kt) {
    // ---- stage K [k][d] and Vt [d][k] (coalesced int4) ----
#pragma unroll
    for (int i = 0; i < 2; ++i) {
      const int cc = t + i * 256;
      const int r8 = cc >> 3, c8 = (cc & 7) * 8;
      *(int4*)&Ks[r8][c8] =
          *(const int4*)(kb + ((size_t)(b * 2048 + kt * 64 + r8)) * 256 + kvh * 64 + c8);
      *(int4*)&Vt[r8][c8] =
          *(const int4*)(vtb + ((size_t)((b * 4 + kvh) * 64 + r8)) * 2048 + kt * 64 + c8);
    }
    __syncthreads();

    const bool needs_mask = (kt * 64 + 63 > q0) || (kt * 64 < q0 + 128 - Wwin);

    // ---- S^T = K Q^T, p = exp(s/8 - 12), pack to Ps[q][k] ----
#pragma unroll
    for (int s = 0; s < 2; ++s) {
      const int qrow = q0 + wave * 32 + s * 16 + l16;
      ushort* prow = &Ps[wave * 32 + s * 16 + l16][0];
#pragma unroll
      for (int nt = 0; nt < 4; ++nt) {
        v8s kf0 = *(const v8s*)&Ks[nt * 16 + l16][quad * 8];
        v8s kf1 = *(const v8s*)&Ks[nt * 16 + l16][32 + quad * 8];
        v4f st = (v4f){0.f, 0.f, 0.f, 0.f};
        st = __builtin_amdgcn_mfma_f32_16x16x32_bf16(kf0, qf[s][0], st, 0, 0, 0);
        st = __builtin_amdgcn_mfma_f32_16x16x32_bf16(kf1, qf[s][1], st, 0, 0, 0);
        float p[4];
#pragma unroll
        for (int r = 0; r < 4; ++r) {
          p[r] = __expf(fmaf(st[r], 0.125f, -12.0f));
          if (needs_mask) {
            const int k = kt * 64 + nt * 16 + quad * 4 + r;
            const bool ok = (k <= qrow) && (k > qrow - Wwin);
            p[r] = ok ? p[r] : 0.0f;
          }
        }
        uint2 w;
        w.x = (uint)f2b(p[0]) | ((uint)f2b(p[1]) << 16);
        w.y = (uint)f2b(p[2]) | ((uint)f2b(p[3]) << 16);
        *(uint2*)(prow + nt * 16 + quad * 4) = w;
      }
    }

    // ---- O += P V (+ ones-row tile dt=4 accumulates l) ----
    v8s pf[2][2];
#pragma unroll
    for (int s = 0; s < 2; ++s) {
      pf[s][0] = *(const v8s*)&Ps[wave * 32 + s * 16 + l16][quad * 8];
      pf[s][1] = *(const v8s*)&Ps[wave * 32 + s * 16 + l16][32 + quad * 8];
    }
#pragma unroll
    for (int dt = 0; dt < 5; ++dt) {
      v8s vf0 = *(const v8s*)&Vt[dt * 16 + l16][quad * 8];
      v8s vf1 = *(const v8s*)&Vt[dt * 16 + l16][32 + quad * 8];
#pragma unroll
      for (int s = 0; s < 2; ++s) {
        o[s][dt] = __builtin_amdgcn_mfma_f32_16x16x32_bf16(pf[s][0], vf0, o[s][dt], 0, 0, 0);
        o[s][dt] = __builtin_amdgcn_mfma_f32_16x16x32_bf16(pf[s][1], vf1, o[s][dt], 0, 0, 0);
      }
    }
    __syncthreads();   // protect Ks/Vt before next staging
  }

  // ---- epilogue: l sits at o[s][4][r] on lanes l16==0; broadcast, divide ----
#pragma unroll
  for (int s = 0; s < 2; ++s)
#pragma unroll
    for (int r = 0; r < 4; ++r) {
      const float l = __shfl(o[s][4][r], lane & 48);
      const float inv = 1.0f / l;
      ushort* yp = yb + ((size_t)(b * 2048 + q0 + wave * 32 + s * 16 + quad * 4 + r)) * 1024
                      + h * 64 + l16;
#pragma unroll
      for (int dt = 0; dt < 4; ++dt) yp[dt * 16] = f2b(o[s][dt][r] * inv);
    }
}

// ---------------------------------------------------------------------------
extern "C" void kernel_launch(void* const* d_in, const int* in_sizes, int n_in,
                              void* d_out, int out_size, void* d_ws, size_t ws_size,
                              hipStream_t stream)
{
  const float* x    = (const float*)d_in[0];
  const float* ve   = (const float*)d_in[1];
  const float* cosp = (const float*)d_in[2];
  const float* sinp = (const float*)d_in[3];
  const float* Wq   = (const float*)d_in[4];
  const float* Wk   = (const float*)d_in[5];
  const float* Wv   = (const float*)d_in[6];
  const float* Wo   = (const float*)d_in[7];
  const float* Wg   = (const float*)d_in[8];
  const int*   win  = (const int*)d_in[9];
  float* out = (float*)d_out;

  char* p = (char*)d_ws;
  float*  qkvws = (float*)p;   p += (size_t)4096 * 1536 * 4;  // 25.2 MB (reused as yb)
  ushort* xb    = (ushort*)p;  p += (size_t)4194304 * 2;      //  8 MB (reused as qb)
  ushort* kb    = (ushort*)p;  p += (size_t)1048576 * 2;      //  2 MB
  ushort* vtb   = (ushort*)p;  p += (size_t)1048576 * 2;      //  2 MB
  ushort* Wqkvt = (ushort*)p;  p += (size_t)1536 * 1024 * 2;  //  3 MB
  ushort* Wot   = (ushort*)p;                                 //  2 MB
  ushort* qb = xb;
  ushort* yb = (ushort*)qkvws;

  cvt_f32_bf16<<<4096, 256, 0, stream>>>(x, xb, 4194304);
  transpose_cvt4<<<dim3(32, 32, 4), 256, 0, stream>>>(
      Wq, Wk, Wv, Wo,
      Wqkvt, Wqkvt + (size_t)1024 * 1024, Wqkvt + (size_t)1280 * 1024, Wot);

  // fused Q|K|V projection: [4096,1024] x [1024,1536]
  gemm_bf16nt<<<dim3(32, 12), 256, 0, stream>>>(xb, Wqkvt, qkvws, 1536, 1024);

  postproc<<<dim3(4096), 256, 0, stream>>>(qkvws, x, ve, cosp, sinp, Wg, qb, kb, vtb);

  attn_mfma<<<dim3(16, 16, 2), 256, 0, stream>>>(qb, kb, vtb, yb, win);

  gemm_bf16nt<<<dim3(32, 8), 256, 0, stream>>>(yb, Wot, out, 1024, 1024);
}

// Round 5
// 177.485 us; speedup vs baseline: 4.3011x; 1.0622x over previous
//
#include <hip/hip_runtime.h>
#include <hip/hip_bf16.h>
#include <cstddef>
#include <cstdint>

// B=2, S=2048, D=1024, H=16, KVH=4, hd=64. window from d_in[9].

typedef short v8s __attribute__((ext_vector_type(8)));
typedef float v4f __attribute__((ext_vector_type(4)));

__device__ __forceinline__ ushort f2b(float f) {
  __hip_bfloat16 h = __float2bfloat16(f);
  return reinterpret_cast<ushort&>(h);
}

// CK-style async global->LDS 16B/lane copy (wave-uniform LDS base + lane*16).
__device__ __forceinline__ void async16(const ushort* g, ushort* l) {
  __builtin_amdgcn_global_load_lds(
      (__attribute__((address_space(1))) void*)(uintptr_t)(const void*)g,
      (__attribute__((address_space(3))) void*)(uintptr_t)(void*)l, 16, 0, 0);
}

// ---------------- x -> bf16 convert + ve-gates ----------------------------
// one block per bs row; threads 0-3 also compute gate[bs][kvh].
__global__ __launch_bounds__(256) void cvt_gate(
    const float* __restrict__ x, ushort* __restrict__ xb,
    const float* __restrict__ Wg, float* __restrict__ gates)
{
  const int bs = blockIdx.x, t = threadIdx.x;
  const float* row = x + (size_t)bs * 1024;
  float4 v = *(const float4*)(row + t * 4);
  ushort4 o;
  o.x = f2b(v.x); o.y = f2b(v.y); o.z = f2b(v.z); o.w = f2b(v.w);
  *(ushort4*)(xb + (size_t)bs * 1024 + t * 4) = o;
  if (t < 4) {
    float g = 0.f;
#pragma unroll
    for (int i = 0; i < 12; ++i) g += row[i] * Wg[i * 4 + t];
    gates[bs * 4 + t] = 3.0f / (1.0f + __expf(-g));
  }
}

// ---------------- pack cos/sin into float2 table ---------------------------
__global__ __launch_bounds__(256) void prep_cs(
    const float* __restrict__ cosp, const float* __restrict__ sinp,
    float2* __restrict__ cs)
{
  const int i = blockIdx.x * 256 + threadIdx.x;   // 65536 total
  cs[i] = make_float2(cosp[i], sinp[i]);
}

// ---------------- 4 weight transposes fused: fp32 [K][N] -> bf16 [N][K] ----
__global__ __launch_bounds__(256) void transpose_cvt4(
    const float* __restrict__ Wq, const float* __restrict__ Wk,
    const float* __restrict__ Wv, const float* __restrict__ Wo,
    ushort* __restrict__ Wqt, ushort* __restrict__ Wkt,
    ushort* __restrict__ Wvt, ushort* __restrict__ Wot)
{
  __shared__ ushort tile[32][33];
  const int z = blockIdx.z;
  const float* W = (z == 0) ? Wq : (z == 1) ? Wo : (z == 2) ? Wk : Wv;
  ushort* Wt     = (z == 0) ? Wqt : (z == 1) ? Wot : (z == 2) ? Wkt : Wvt;
  const int N = (z < 2) ? 1024 : 256;
  const int n0 = blockIdx.x * 32, k0 = blockIdx.y * 32;
  if (n0 >= N) return;
  const int tx = threadIdx.x & 31, ty = threadIdx.x >> 5;
#pragma unroll
  for (int i = 0; i < 4; ++i) {
    const int k = ty + i * 8;
    tile[k][tx] = f2b(W[(size_t)(k0 + k) * N + n0 + tx]);
  }
  __syncthreads();
#pragma unroll
  for (int i = 0; i < 4; ++i) {
    const int n = ty + i * 8;
    Wt[(size_t)(n0 + n) * 1024 + k0 + tx] = tile[tx][n];
  }
}

// ---------------- GEMM mainloop: async-LDS staged, 128x128, BK=64 ----------
// As/Bs unpadded [128][64] (m97 structure). acc[mt][nt], C row =
// m0+wr*64+mt*16+quad*4+r, col = n0+wc*64+nt*16+l16 (verified r2).
__device__ __forceinline__ void gemm_mainloop(
    const ushort* __restrict__ A, const ushort* __restrict__ Bt,
    int K, int m0, int n0, ushort (*As)[64], ushort (*Bs)[64],
    v4f acc[4][4])
{
  const int t = threadIdx.x;
  const int lane = t & 63, wave = t >> 6;
  const int wr = wave >> 1, wc = wave & 1;
  const int quad = lane >> 4, l16 = lane & 15;
  const int l8 = lane >> 3, c8 = (lane & 7) * 8;

  const ushort* ap[4];
  const ushort* bp[4];
  ushort* al[4];
  ushort* bl[4];
#pragma unroll
  for (int i = 0; i < 4; ++i) {
    const int row = (wave * 4 + i) * 8 + l8;
    ap[i] = A  + (size_t)(m0 + row) * K + c8;
    bp[i] = Bt + (size_t)(n0 + row) * K + c8;
    al[i] = &As[(wave * 4 + i) * 8][0];
    bl[i] = &Bs[(wave * 4 + i) * 8][0];
  }

  for (int k0 = 0; k0 < K; k0 += 64) {
#pragma unroll
    for (int i = 0; i < 4; ++i) {
      async16(ap[i] + k0, al[i]);
      async16(bp[i] + k0, bl[i]);
    }
    __syncthreads();   // drains vmcnt (global_load_lds) before frag reads
#pragma unroll
    for (int ks = 0; ks < 2; ++ks) {
      v8s af[4], bf[4];
#pragma unroll
      for (int i = 0; i < 4; ++i) {
        af[i] = *(const v8s*)&As[wr * 64 + i * 16 + l16][ks * 32 + quad * 8];
        bf[i] = *(const v8s*)&Bs[wc * 64 + i * 16 + l16][ks * 32 + quad * 8];
      }
#pragma unroll
      for (int mt = 0; mt < 4; ++mt)
#pragma unroll
        for (int nt = 0; nt < 4; ++nt)
          acc[mt][nt] = __builtin_amdgcn_mfma_f32_16x16x32_bf16(
              af[mt], bf[nt], acc[mt][nt], 0, 0, 0);
    }
    __syncthreads();
  }
}

// ---------------- QKV GEMM with fused rope/rmsnorm/gate epilogue -----------
// A = xb [4096][1024], Bt = Wqkvt [1536][1024]. Section by blockIdx.y:
// 0-7 -> Q heads, 8-9 -> K heads, 10-11 -> V heads.
__global__ __launch_bounds__(256) void gemm_qkv_fused(
    const ushort* __restrict__ A, const ushort* __restrict__ Bt,
    const float2* __restrict__ cs, const float* __restrict__ gates,
    const float* __restrict__ ve,
    ushort* __restrict__ qb, ushort* __restrict__ kb, ushort* __restrict__ vb)
{
  __shared__ ushort As[128][64];
  __shared__ ushort Bs[128][64];
  const int m0 = blockIdx.x * 128, n0 = blockIdx.y * 128;
  const int lane = threadIdx.x & 63, wave = threadIdx.x >> 6;
  const int wr = wave >> 1, wc = wave & 1;
  const int quad = lane >> 4, l16 = lane & 15;

  v4f acc[4][4];
#pragma unroll
  for (int i = 0; i < 4; ++i)
#pragma unroll
    for (int j = 0; j < 4; ++j) acc[i][j] = (v4f){0.f, 0.f, 0.f, 0.f};

  gemm_mainloop(A, Bt, 1024, m0, n0, As, Bs, acc);

  const int sec = blockIdx.y;
  const int head_col = n0 + wc * 64;

  if (sec < 10) {
    // ---- Q or K: rope + rmsnorm*1.2, write bf16 ----
    const bool isQ = (sec < 8);
    const int h = (head_col - (isQ ? 0 : 1024)) >> 6;
    ushort* dst = isQ ? qb : kb;
    const int ld = isQ ? 1024 : 256;
#pragma unroll
    for (int mt = 0; mt < 4; ++mt)
#pragma unroll
      for (int r = 0; r < 4; ++r) {
        const int row = m0 + wr * 64 + mt * 16 + quad * 4 + r;
        const int s = row & 2047;
        const float2 cs0 = cs[s * 32 + l16];
        const float2 cs1 = cs[s * 32 + 16 + l16];
        const float x10 = acc[mt][0][r], x11 = acc[mt][1][r];
        const float x20 = acc[mt][2][r], x21 = acc[mt][3][r];
        // rotation preserves norms: reduce pre-rope values
        float ss = x10 * x10 + x11 * x11 + x20 * x20 + x21 * x21;
        ss += __shfl_xor(ss, 1);
        ss += __shfl_xor(ss, 2);
        ss += __shfl_xor(ss, 4);
        ss += __shfl_xor(ss, 8);
        const float rs = rsqrtf(ss * (1.0f / 64.0f) + 1e-6f) * 1.2f;
        ushort* dp = dst + (size_t)row * ld + h * 64 + l16;
        dp[0]  = f2b((x10 * cs0.x + x20 * cs0.y) * rs);
        dp[16] = f2b((x11 * cs1.x + x21 * cs1.y) * rs);
        dp[32] = f2b((-x10 * cs0.y + x20 * cs0.x) * rs);
        dp[48] = f2b((-x11 * cs1.y + x21 * cs1.x) * rs);
      }
  } else {
    // ---- V: + gate * ve, write bf16 ----
    const int kvh = (head_col - 1280) >> 6;
#pragma unroll
    for (int mt = 0; mt < 4; ++mt)
#pragma unroll
      for (int r = 0; r < 4; ++r) {
        const int row = m0 + wr * 64 + mt * 16 + quad * 4 + r;
        const float gate = gates[row * 4 + kvh];
        const float* vep = ve + (size_t)row * 256 + kvh * 64 + l16;
        ushort* dp = vb + (size_t)row * 256 + kvh * 64 + l16;
#pragma unroll
        for (int nt = 0; nt < 4; ++nt)
          dp[nt * 16] = f2b(acc[mt][nt][r] + gate * vep[nt * 16]);
      }
  }
}

// ---------------- Wo GEMM: plain fp32 epilogue -----------------------------
__global__ __launch_bounds__(256) void gemm_wo(
    const ushort* __restrict__ A, const ushort* __restrict__ Bt,
    float* __restrict__ C)
{
  __shared__ ushort As[128][64];
  __shared__ ushort Bs[128][64];
  const int m0 = blockIdx.x * 128, n0 = blockIdx.y * 128;
  const int lane = threadIdx.x & 63, wave = threadIdx.x >> 6;
  const int wr = wave >> 1, wc = wave & 1;
  const int quad = lane >> 4, l16 = lane & 15;

  v4f acc[4][4];
#pragma unroll
  for (int i = 0; i < 4; ++i)
#pragma unroll
    for (int j = 0; j < 4; ++j) acc[i][j] = (v4f){0.f, 0.f, 0.f, 0.f};

  gemm_mainloop(A, Bt, 1024, m0, n0, As, Bs, acc);

#pragma unroll
  for (int mt = 0; mt < 4; ++mt)
#pragma unroll
    for (int r = 0; r < 4; ++r) {
      float* cp = C + (size_t)(m0 + wr * 64 + mt * 16 + quad * 4 + r) * 1024
                    + n0 + wc * 64 + l16;
#pragma unroll
      for (int nt = 0; nt < 4; ++nt) cp[nt * 16] = acc[mt][nt][r];
    }
}

// ---------------- vb [bs][kvh*64+d] -> vtb [b][kvh][d][s] ------------------
__global__ __launch_bounds__(256) void transpose_v(
    const ushort* __restrict__ vb, ushort* __restrict__ vtb)
{
  __shared__ ushort L[64][72];
  const int s0 = blockIdx.x * 64, kvh = blockIdx.y, b = blockIdx.z;
  const int t = threadIdx.x;
#pragma unroll
  for (int i = 0; i < 2; ++i) {
    const int cc = t + i * 256;
    const int srow = cc >> 3, c8 = (cc & 7) * 8;
    *(int4*)&L[srow][c8] =
        *(const int4*)(vb + ((size_t)(b * 2048 + s0 + srow)) * 256 + kvh * 64 + c8);
  }
  __syncthreads();
#pragma unroll
  for (int i = 0; i < 2; ++i) {
    const int cc = t + i * 256;
    const int drow = cc >> 3, s8 = (cc & 7) * 8;
    ushort w[8];
#pragma unroll
    for (int jj = 0; jj < 8; ++jj) w[jj] = L[s8 + jj][drow];
    *(int4*)(vtb + ((size_t)((b * 4 + kvh) * 64 + drow)) * 2048 + s0 + s8) =
        *(int4*)w;
  }
}

// ---------------- MFMA flash attention, fixed-max softmax (r4, verified) ---
__global__ __launch_bounds__(256) void attn_mfma(
    const ushort* __restrict__ qb, const ushort* __restrict__ kb,
    const ushort* __restrict__ vtb, ushort* __restrict__ yb,
    const int* __restrict__ wptr)
{
  __shared__ ushort Ks[64][72];
  __shared__ ushort Vt[80][72];
  __shared__ ushort Ps[128][72];
  const int qt = blockIdx.x, h = blockIdx.y, b = blockIdx.z;
  const int kvh = h >> 2, q0 = qt * 128;
  const int t = threadIdx.x, lane = t & 63, wave = t >> 6;
  const int quad = lane >> 4, l16 = lane & 15;
  const int Wwin = *wptr;

  v8s qf[2][2];
#pragma unroll
  for (int s = 0; s < 2; ++s) {
    const ushort* qp = qb + ((size_t)(b * 2048 + q0 + wave * 32 + s * 16 + l16)) * 1024
                          + h * 64 + quad * 8;
    qf[s][0] = *(const v8s*)qp;
    qf[s][1] = *(const v8s*)(qp + 32);
  }

  if (t < 128) {
    const int row = 64 + (t >> 3), c8 = (t & 7) * 8;
    const int v = (row == 64) ? 0x3F803F80 : 0;
    int4 w; w.x = v; w.y = v; w.z = v; w.w = v;
    *(int4*)&Vt[row][c8] = w;
  }

  v4f o[2][5];
#pragma unroll
  for (int s = 0; s < 2; ++s)
#pragma unroll
    for (int d = 0; d < 5; ++d) o[s][d] = (v4f){0.f, 0.f, 0.f, 0.f};

  const int lo = q0 - Wwin + 1;
  const int kt0 = (lo > 0) ? (lo >> 6) : 0;
  const int kt1 = (q0 + 127) >> 6;

  for (int kt = kt0; kt <= kt1; ++kt) {
#pragma unroll
    for (int i = 0; i < 2; ++i) {
      const int cc = t + i * 256;
      const int r8 = cc >> 3, c8 = (cc & 7) * 8;
      *(int4*)&Ks[r8][c8] =
          *(const int4*)(kb + ((size_t)(b * 2048 + kt * 64 + r8)) * 256 + kvh * 64 + c8);
      *(int4*)&Vt[r8][c8] =
          *(const int4*)(vtb + ((size_t)((b * 4 + kvh) * 64 + r8)) * 2048 + kt * 64 + c8);
    }
    __syncthreads();

    const bool needs_mask = (kt * 64 + 63 > q0) || (kt * 64 < q0 + 128 - Wwin);

#pragma unroll
    for (int s = 0; s < 2; ++s) {
      const int qrow = q0 + wave * 32 + s * 16 + l16;
      ushort* prow = &Ps[wave * 32 + s * 16 + l16][0];
#pragma unroll
      for (int nt = 0; nt < 4; ++nt) {
        v8s kf0 = *(const v8s*)&Ks[nt * 16 + l16][quad * 8];
        v8s kf1 = *(const v8s*)&Ks[nt * 16 + l16][32 + quad * 8];
        v4f st = (v4f){0.f, 0.f, 0.f, 0.f};
        st = __builtin_amdgcn_mfma_f32_16x16x32_bf16(kf0, qf[s][0], st, 0, 0, 0);
        st = __builtin_amdgcn_mfma_f32_16x16x32_bf16(kf1, qf[s][1], st, 0, 0, 0);
        float p[4];
#pragma unroll
        for (int r = 0; r < 4; ++r) {
          p[r] = __expf(fmaf(st[r], 0.125f, -12.0f));
          if (needs_mask) {
            const int k = kt * 64 + nt * 16 + quad * 4 + r;
            const bool ok = (k <= qrow) && (k > qrow - Wwin);
            p[r] = ok ? p[r] : 0.0f;
          }
        }
        uint2 w;
        w.x = (uint)f2b(p[0]) | ((uint)f2b(p[1]) << 16);
        w.y = (uint)f2b(p[2]) | ((uint)f2b(p[3]) << 16);
        *(uint2*)(prow + nt * 16 + quad * 4) = w;
      }
    }

    v8s pf[2][2];
#pragma unroll
    for (int s = 0; s < 2; ++s) {
      pf[s][0] = *(const v8s*)&Ps[wave * 32 + s * 16 + l16][quad * 8];
      pf[s][1] = *(const v8s*)&Ps[wave * 32 + s * 16 + l16][32 + quad * 8];
    }
#pragma unroll
    for (int dt = 0; dt < 5; ++dt) {
      v8s vf0 = *(const v8s*)&Vt[dt * 16 + l16][quad * 8];
      v8s vf1 = *(const v8s*)&Vt[dt * 16 + l16][32 + quad * 8];
#pragma unroll
      for (int s = 0; s < 2; ++s) {
        o[s][dt] = __builtin_amdgcn_mfma_f32_16x16x32_bf16(pf[s][0], vf0, o[s][dt], 0, 0, 0);
        o[s][dt] = __builtin_amdgcn_mfma_f32_16x16x32_bf16(pf[s][1], vf1, o[s][dt], 0, 0, 0);
      }
    }
    __syncthreads();
  }

#pragma unroll
  for (int s = 0; s < 2; ++s)
#pragma unroll
    for (int r = 0; r < 4; ++r) {
      const float l = __shfl(o[s][4][r], lane & 48);
      const float inv = 1.0f / l;
      ushort* yp = yb + ((size_t)(b * 2048 + q0 + wave * 32 + s * 16 + quad * 4 + r)) * 1024
                      + h * 64 + l16;
#pragma unroll
      for (int dt = 0; dt < 4; ++dt) yp[dt * 16] = f2b(o[s][dt][r] * inv);
    }
}

// ---------------------------------------------------------------------------
extern "C" void kernel_launch(void* const* d_in, const int* in_sizes, int n_in,
                              void* d_out, int out_size, void* d_ws, size_t ws_size,
                              hipStream_t stream)
{
  const float* x    = (const float*)d_in[0];
  const float* ve   = (const float*)d_in[1];
  const float* cosp = (const float*)d_in[2];
  const float* sinp = (const float*)d_in[3];
  const float* Wq   = (const float*)d_in[4];
  const float* Wk   = (const float*)d_in[5];
  const float* Wv   = (const float*)d_in[6];
  const float* Wo   = (const float*)d_in[7];
  const float* Wg   = (const float*)d_in[8];
  const int*   win  = (const int*)d_in[9];
  float* out = (float*)d_out;

  char* p = (char*)d_ws;
  ushort* xb    = (ushort*)p;  p += (size_t)4194304 * 2;      //  8 MB
  ushort* qb    = (ushort*)p;  p += (size_t)4194304 * 2;      //  8 MB
  ushort* yb    = (ushort*)p;  p += (size_t)4194304 * 2;      //  8 MB
  ushort* kb    = (ushort*)p;  p += (size_t)1048576 * 2;      //  2 MB
  ushort* vb    = (ushort*)p;  p += (size_t)1048576 * 2;      //  2 MB
  ushort* vtb   = (ushort*)p;  p += (size_t)1048576 * 2;      //  2 MB
  ushort* Wqkvt = (ushort*)p;  p += (size_t)1536 * 1024 * 2;  //  3 MB
  ushort* Wot   = (ushort*)p;  p += (size_t)1048576 * 2;      //  2 MB
  float2* cs    = (float2*)p;  p += (size_t)65536 * 8;        // .5 MB
  float*  gates = (float*)p;                                  // 64 KB

  cvt_gate<<<4096, 256, 0, stream>>>(x, xb, Wg, gates);
  prep_cs<<<256, 256, 0, stream>>>(cosp, sinp, cs);
  transpose_cvt4<<<dim3(32, 32, 4), 256, 0, stream>>>(
      Wq, Wk, Wv, Wo,
      Wqkvt, Wqkvt + (size_t)1024 * 1024, Wqkvt + (size_t)1280 * 1024, Wot);

  // fused QKV projection + rope/rmsnorm/gate epilogue
  gemm_qkv_fused<<<dim3(32, 12), 256, 0, stream>>>(xb, Wqkvt, cs, gates, ve,
                                                   qb, kb, vb);
  transpose_v<<<dim3(32, 4, 2), 256, 0, stream>>>(vb, vtb);

  attn_mfma<<<dim3(16, 16, 2), 256, 0, stream>>>(qb, kb, vtb, yb, win);

  gemm_wo<<<dim3(32, 8), 256, 0, stream>>>(yb, Wot, out);
}

// Round 6
// 174.484 us; speedup vs baseline: 4.3751x; 1.0172x over previous
//
#include <hip/hip_runtime.h>
#include <hip/hip_bf16.h>
#include <cstddef>
#include <cstdint>

// B=2, S=2048, D=1024, H=16, KVH=4, hd=64. window from d_in[9].

typedef short v8s __attribute__((ext_vector_type(8)));
typedef float v4f __attribute__((ext_vector_type(4)));

// Exact RNE fp32->bf16 for FINITE values (no NaN path): 3 VALU ops.
__device__ __forceinline__ ushort b1(float a) {
  uint u = __float_as_uint(a);
  return (ushort)((u + 0x7FFFu + ((u >> 16) & 1u)) >> 16);
}
// Packed pair (lo, hi) -> one uint.
__device__ __forceinline__ uint bpack(float lo, float hi) {
  uint ul = __float_as_uint(lo), uh = __float_as_uint(hi);
  ul = (ul + 0x7FFFu + ((ul >> 16) & 1u)) >> 16;
  uh = (uh + 0x7FFFu + ((uh >> 16) & 1u)) & 0xFFFF0000u;
  return ul | uh;
}

// CK-style async global->LDS 16B/lane copy (wave-uniform LDS base + lane*16).
__device__ __forceinline__ void async16(const ushort* g, ushort* l) {
  __builtin_amdgcn_global_load_lds(
      (__attribute__((address_space(1))) void*)(uintptr_t)(const void*)g,
      (__attribute__((address_space(3))) void*)(uintptr_t)(void*)l, 16, 0, 0);
}

// ---------------- merged prep: x-cvt+gates | cs pack | 4 weight transposes --
// blocks 0..4095: x->bf16 + gates; 4096..4351: cs pack; 4352..6911: transposes.
__global__ __launch_bounds__(256) void prep_all(
    const float* __restrict__ x, ushort* __restrict__ xb,
    const float* __restrict__ Wg, float* __restrict__ gates,
    const float* __restrict__ cosp, const float* __restrict__ sinp,
    float2* __restrict__ cs,
    const float* __restrict__ Wq, const float* __restrict__ Wk,
    const float* __restrict__ Wv, const float* __restrict__ Wo,
    ushort* __restrict__ Wqt, ushort* __restrict__ Wkt,
    ushort* __restrict__ Wvt, ushort* __restrict__ Wot)
{
  const int bx = blockIdx.x, t = threadIdx.x;
  if (bx < 4096) {
    const float* row = x + (size_t)bx * 1024;
    float4 v = *(const float4*)(row + t * 4);
    ushort4 o;
    o.x = b1(v.x); o.y = b1(v.y); o.z = b1(v.z); o.w = b1(v.w);
    *(ushort4*)(xb + (size_t)bx * 1024 + t * 4) = o;
    if (t < 4) {
      float g = 0.f;
#pragma unroll
      for (int i = 0; i < 12; ++i) g += row[i] * Wg[i * 4 + t];
      gates[bx * 4 + t] = 3.0f / (1.0f + __expf(-g));
    }
    return;
  }
  if (bx < 4352) {
    const int i = (bx - 4096) * 256 + t;   // 65536 total
    cs[i] = make_float2(cosp[i], sinp[i]);
    return;
  }
  // transpose sections
  __shared__ ushort tile[32][33];
  int u = bx - 4352;
  const float* W; ushort* Wt; int N, xx, yy;
  if (u < 1024)      { W = Wq; Wt = Wqt; N = 1024; xx = u & 31; yy = u >> 5; }
  else if (u < 2048) { u -= 1024; W = Wo; Wt = Wot; N = 1024; xx = u & 31; yy = u >> 5; }
  else if (u < 2304) { u -= 2048; W = Wk; Wt = Wkt; N = 256;  xx = u & 7;  yy = u >> 3; }
  else               { u -= 2304; W = Wv; Wt = Wvt; N = 256;  xx = u & 7;  yy = u >> 3; }
  const int n0 = xx * 32, k0 = yy * 32;
  const int tx = t & 31, ty = t >> 5;
#pragma unroll
  for (int i = 0; i < 4; ++i) {
    const int k = ty + i * 8;
    tile[k][tx] = b1(W[(size_t)(k0 + k) * N + n0 + tx]);
  }
  __syncthreads();
#pragma unroll
  for (int i = 0; i < 4; ++i) {
    const int n = ty + i * 8;
    Wt[(size_t)(n0 + n) * 1024 + k0 + tx] = tile[tx][n];
  }
}

// ---------------- GEMM mainloop: async-LDS staged, 128x128, BK=64 ----------
__device__ __forceinline__ void gemm_mainloop(
    const ushort* __restrict__ A, const ushort* __restrict__ Bt,
    int K, int m0, int n0, ushort (*As)[64], ushort (*Bs)[64],
    v4f acc[4][4])
{
  const int t = threadIdx.x;
  const int lane = t & 63, wave = t >> 6;
  const int wr = wave >> 1, wc = wave & 1;
  const int quad = lane >> 4, l16 = lane & 15;
  const int l8 = lane >> 3, c8 = (lane & 7) * 8;

  const ushort* ap[4];
  const ushort* bp[4];
  ushort* al[4];
  ushort* bl[4];
#pragma unroll
  for (int i = 0; i < 4; ++i) {
    const int row = (wave * 4 + i) * 8 + l8;
    ap[i] = A  + (size_t)(m0 + row) * K + c8;
    bp[i] = Bt + (size_t)(n0 + row) * K + c8;
    al[i] = &As[(wave * 4 + i) * 8][0];
    bl[i] = &Bs[(wave * 4 + i) * 8][0];
  }

  for (int k0 = 0; k0 < K; k0 += 64) {
#pragma unroll
    for (int i = 0; i < 4; ++i) {
      async16(ap[i] + k0, al[i]);
      async16(bp[i] + k0, bl[i]);
    }
    __syncthreads();
#pragma unroll
    for (int ks = 0; ks < 2; ++ks) {
      v8s af[4], bf[4];
#pragma unroll
      for (int i = 0; i < 4; ++i) {
        af[i] = *(const v8s*)&As[wr * 64 + i * 16 + l16][ks * 32 + quad * 8];
        bf[i] = *(const v8s*)&Bs[wc * 64 + i * 16 + l16][ks * 32 + quad * 8];
      }
#pragma unroll
      for (int mt = 0; mt < 4; ++mt)
#pragma unroll
        for (int nt = 0; nt < 4; ++nt)
          acc[mt][nt] = __builtin_amdgcn_mfma_f32_16x16x32_bf16(
              af[mt], bf[nt], acc[mt][nt], 0, 0, 0);
    }
    __syncthreads();
  }
}

// ---------------- QKV GEMM with fused rope/rmsnorm/gate epilogue -----------
__global__ __launch_bounds__(256) void gemm_qkv_fused(
    const ushort* __restrict__ A, const ushort* __restrict__ Bt,
    const float2* __restrict__ cs, const float* __restrict__ gates,
    const float* __restrict__ ve,
    ushort* __restrict__ qb, ushort* __restrict__ kb, ushort* __restrict__ vb)
{
  __shared__ ushort As[128][64];
  __shared__ ushort Bs[128][64];
  const int m0 = blockIdx.x * 128, n0 = blockIdx.y * 128;
  const int lane = threadIdx.x & 63, wave = threadIdx.x >> 6;
  const int wr = wave >> 1, wc = wave & 1;
  const int quad = lane >> 4, l16 = lane & 15;

  v4f acc[4][4];
#pragma unroll
  for (int i = 0; i < 4; ++i)
#pragma unroll
    for (int j = 0; j < 4; ++j) acc[i][j] = (v4f){0.f, 0.f, 0.f, 0.f};

  gemm_mainloop(A, Bt, 1024, m0, n0, As, Bs, acc);

  const int sec = blockIdx.y;
  const int head_col = n0 + wc * 64;

  if (sec < 10) {
    const bool isQ = (sec < 8);
    const int h = (head_col - (isQ ? 0 : 1024)) >> 6;
    ushort* dst = isQ ? qb : kb;
    const int ld = isQ ? 1024 : 256;
#pragma unroll
    for (int mt = 0; mt < 4; ++mt)
#pragma unroll
      for (int r = 0; r < 4; ++r) {
        const int row = m0 + wr * 64 + mt * 16 + quad * 4 + r;
        const int s = row & 2047;
        const float2 cs0 = cs[s * 32 + l16];
        const float2 cs1 = cs[s * 32 + 16 + l16];
        const float x10 = acc[mt][0][r], x11 = acc[mt][1][r];
        const float x20 = acc[mt][2][r], x21 = acc[mt][3][r];
        float ss = x10 * x10 + x11 * x11 + x20 * x20 + x21 * x21;
        ss += __shfl_xor(ss, 1);
        ss += __shfl_xor(ss, 2);
        ss += __shfl_xor(ss, 4);
        ss += __shfl_xor(ss, 8);
        const float rs = rsqrtf(ss * (1.0f / 64.0f) + 1e-6f) * 1.2f;
        ushort* dp = dst + (size_t)row * ld + h * 64 + l16;
        dp[0]  = b1((x10 * cs0.x + x20 * cs0.y) * rs);
        dp[16] = b1((x11 * cs1.x + x21 * cs1.y) * rs);
        dp[32] = b1((-x10 * cs0.y + x20 * cs0.x) * rs);
        dp[48] = b1((-x11 * cs1.y + x21 * cs1.x) * rs);
      }
  } else {
    const int kvh = (head_col - 1280) >> 6;
#pragma unroll
    for (int mt = 0; mt < 4; ++mt)
#pragma unroll
      for (int r = 0; r < 4; ++r) {
        const int row = m0 + wr * 64 + mt * 16 + quad * 4 + r;
        const float gate = gates[row * 4 + kvh];
        const float* vep = ve + (size_t)row * 256 + kvh * 64 + l16;
        ushort* dp = vb + (size_t)row * 256 + kvh * 64 + l16;
#pragma unroll
        for (int nt = 0; nt < 4; ++nt)
          dp[nt * 16] = b1(acc[mt][nt][r] + gate * vep[nt * 16]);
      }
  }
}

// ---------------- Wo GEMM: plain fp32 epilogue -----------------------------
__global__ __launch_bounds__(256) void gemm_wo(
    const ushort* __restrict__ A, const ushort* __restrict__ Bt,
    float* __restrict__ C)
{
  __shared__ ushort As[128][64];
  __shared__ ushort Bs[128][64];
  const int m0 = blockIdx.x * 128, n0 = blockIdx.y * 128;
  const int lane = threadIdx.x & 63, wave = threadIdx.x >> 6;
  const int wr = wave >> 1, wc = wave & 1;
  const int quad = lane >> 4, l16 = lane & 15;

  v4f acc[4][4];
#pragma unroll
  for (int i = 0; i < 4; ++i)
#pragma unroll
    for (int j = 0; j < 4; ++j) acc[i][j] = (v4f){0.f, 0.f, 0.f, 0.f};

  gemm_mainloop(A, Bt, 1024, m0, n0, As, Bs, acc);

#pragma unroll
  for (int mt = 0; mt < 4; ++mt)
#pragma unroll
    for (int r = 0; r < 4; ++r) {
      float* cp = C + (size_t)(m0 + wr * 64 + mt * 16 + quad * 4 + r) * 1024
                    + n0 + wc * 64 + l16;
#pragma unroll
      for (int nt = 0; nt < 4; ++nt) cp[nt * 16] = acc[mt][nt][r];
    }
}

// ---------------- vb [bs][kvh*64+d] -> vtb [b][kvh][d][s] ------------------
__global__ __launch_bounds__(256) void transpose_v(
    const ushort* __restrict__ vb, ushort* __restrict__ vtb)
{
  __shared__ ushort L[64][72];
  const int s0 = blockIdx.x * 64, kvh = blockIdx.y, b = blockIdx.z;
  const int t = threadIdx.x;
#pragma unroll
  for (int i = 0; i < 2; ++i) {
    const int cc = t + i * 256;
    const int srow = cc >> 3, c8 = (cc & 7) * 8;
    *(int4*)&L[srow][c8] =
        *(const int4*)(vb + ((size_t)(b * 2048 + s0 + srow)) * 256 + kvh * 64 + c8);
  }
  __syncthreads();
#pragma unroll
  for (int i = 0; i < 2; ++i) {
    const int cc = t + i * 256;
    const int drow = cc >> 3, s8 = (cc & 7) * 8;
    ushort w[8];
#pragma unroll
    for (int jj = 0; jj < 8; ++jj) w[jj] = L[s8 + jj][drow];
    *(int4*)(vtb + ((size_t)((b * 4 + kvh) * 64 + drow)) * 2048 + s0 + s8) =
        *(int4*)w;
  }
}

// ---------------- MFMA flash attention, fixed-max softmax ------------------
// p = exp2(s*0.125*log2e - 12*log2e), exact shift of softmax (bound 11.52).
__global__ __launch_bounds__(256) void attn_mfma(
    const ushort* __restrict__ qb, const ushort* __restrict__ kb,
    const ushort* __restrict__ vtb, ushort* __restrict__ yb,
    const int* __restrict__ wptr)
{
  __shared__ ushort Ks[64][72];
  __shared__ ushort Vt[80][72];
  __shared__ ushort Ps[128][72];
  const int qt = blockIdx.x, h = blockIdx.y, b = blockIdx.z;
  const int kvh = h >> 2, q0 = qt * 128;
  const int t = threadIdx.x, lane = t & 63, wave = t >> 6;
  const int quad = lane >> 4, l16 = lane & 15;
  const int Wwin = *wptr;

  v8s qf[2][2];
#pragma unroll
  for (int s = 0; s < 2; ++s) {
    const ushort* qp = qb + ((size_t)(b * 2048 + q0 + wave * 32 + s * 16 + l16)) * 1024
                          + h * 64 + quad * 8;
    qf[s][0] = *(const v8s*)qp;
    qf[s][1] = *(const v8s*)(qp + 32);
  }

  if (t < 128) {
    const int row = 64 + (t >> 3), c8 = (t & 7) * 8;
    const int v = (row == 64) ? 0x3F803F80 : 0;
    int4 w; w.x = v; w.y = v; w.z = v; w.w = v;
    *(int4*)&Vt[row][c8] = w;
  }

  v4f o[2][5];
#pragma unroll
  for (int s = 0; s < 2; ++s)
#pragma unroll
    for (int d = 0; d < 5; ++d) o[s][d] = (v4f){0.f, 0.f, 0.f, 0.f};

  const int lo = q0 - Wwin + 1;
  const int kt0 = (lo > 0) ? (lo >> 6) : 0;
  const int kt1 = (q0 + 127) >> 6;

  for (int kt = kt0; kt <= kt1; ++kt) {
#pragma unroll
    for (int i = 0; i < 2; ++i) {
      const int cc = t + i * 256;
      const int r8 = cc >> 3, c8 = (cc & 7) * 8;
      *(int4*)&Ks[r8][c8] =
          *(const int4*)(kb + ((size_t)(b * 2048 + kt * 64 + r8)) * 256 + kvh * 64 + c8);
      *(int4*)&Vt[r8][c8] =
          *(const int4*)(vtb + ((size_t)((b * 4 + kvh) * 64 + r8)) * 2048 + kt * 64 + c8);
    }
    __syncthreads();

    const bool needs_mask = (kt * 64 + 63 > q0) || (kt * 64 < q0 + 128 - Wwin);

#pragma unroll
    for (int s = 0; s < 2; ++s) {
      const int qrow = q0 + wave * 32 + s * 16 + l16;
      ushort* prow = &Ps[wave * 32 + s * 16 + l16][0];
#pragma unroll
      for (int nt = 0; nt < 4; ++nt) {
        v8s kf0 = *(const v8s*)&Ks[nt * 16 + l16][quad * 8];
        v8s kf1 = *(const v8s*)&Ks[nt * 16 + l16][32 + quad * 8];
        v4f st = (v4f){0.f, 0.f, 0.f, 0.f};
        st = __builtin_amdgcn_mfma_f32_16x16x32_bf16(kf0, qf[s][0], st, 0, 0, 0);
        st = __builtin_amdgcn_mfma_f32_16x16x32_bf16(kf1, qf[s][1], st, 0, 0, 0);
        float p[4];
#pragma unroll
        for (int r = 0; r < 4; ++r) {
          // 0.125*log2e, 12*log2e
          p[r] = exp2f(fmaf(st[r], 0.18033688011f, -17.31234049107f));
          if (needs_mask) {
            const int k = kt * 64 + nt * 16 + quad * 4 + r;
            const bool ok = (k <= qrow) && (k > qrow - Wwin);
            p[r] = ok ? p[r] : 0.0f;
          }
        }
        uint2 w;
        w.x = bpack(p[0], p[1]);
        w.y = bpack(p[2], p[3]);
        *(uint2*)(prow + nt * 16 + quad * 4) = w;
      }
    }

    v8s pf[2][2];
#pragma unroll
    for (int s = 0; s < 2; ++s) {
      pf[s][0] = *(const v8s*)&Ps[wave * 32 + s * 16 + l16][quad * 8];
      pf[s][1] = *(const v8s*)&Ps[wave * 32 + s * 16 + l16][32 + quad * 8];
    }
#pragma unroll
    for (int dt = 0; dt < 5; ++dt) {
      v8s vf0 = *(const v8s*)&Vt[dt * 16 + l16][quad * 8];
      v8s vf1 = *(const v8s*)&Vt[dt * 16 + l16][32 + quad * 8];
#pragma unroll
      for (int s = 0; s < 2; ++s) {
        o[s][dt] = __builtin_amdgcn_mfma_f32_16x16x32_bf16(pf[s][0], vf0, o[s][dt], 0, 0, 0);
        o[s][dt] = __builtin_amdgcn_mfma_f32_16x16x32_bf16(pf[s][1], vf1, o[s][dt], 0, 0, 0);
      }
    }
    __syncthreads();
  }

#pragma unroll
  for (int s = 0; s < 2; ++s)
#pragma unroll
    for (int r = 0; r < 4; ++r) {
      const float l = __shfl(o[s][4][r], lane & 48);
      const float inv = 1.0f / l;
      ushort* yp = yb + ((size_t)(b * 2048 + q0 + wave * 32 + s * 16 + quad * 4 + r)) * 1024
                      + h * 64 + l16;
#pragma unroll
      for (int dt = 0; dt < 4; ++dt) yp[dt * 16] = b1(o[s][dt][r] * inv);
    }
}

// ---------------------------------------------------------------------------
extern "C" void kernel_launch(void* const* d_in, const int* in_sizes, int n_in,
                              void* d_out, int out_size, void* d_ws, size_t ws_size,
                              hipStream_t stream)
{
  const float* x    = (const float*)d_in[0];
  const float* ve   = (const float*)d_in[1];
  const float* cosp = (const float*)d_in[2];
  const float* sinp = (const float*)d_in[3];
  const float* Wq   = (const float*)d_in[4];
  const float* Wk   = (const float*)d_in[5];
  const float* Wv   = (const float*)d_in[6];
  const float* Wo   = (const float*)d_in[7];
  const float* Wg   = (const float*)d_in[8];
  const int*   win  = (const int*)d_in[9];
  float* out = (float*)d_out;

  char* p = (char*)d_ws;
  ushort* xb    = (ushort*)p;  p += (size_t)4194304 * 2;      //  8 MB
  ushort* qb    = (ushort*)p;  p += (size_t)4194304 * 2;      //  8 MB
  ushort* yb    = (ushort*)p;  p += (size_t)4194304 * 2;      //  8 MB
  ushort* kb    = (ushort*)p;  p += (size_t)1048576 * 2;      //  2 MB
  ushort* vb    = (ushort*)p;  p += (size_t)1048576 * 2;      //  2 MB
  ushort* vtb   = (ushort*)p;  p += (size_t)1048576 * 2;      //  2 MB
  ushort* Wqkvt = (ushort*)p;  p += (size_t)1536 * 1024 * 2;  //  3 MB
  ushort* Wot   = (ushort*)p;  p += (size_t)1048576 * 2;      //  2 MB
  float2* cs    = (float2*)p;  p += (size_t)65536 * 8;        // .5 MB
  float*  gates = (float*)p;                                  // 64 KB

  prep_all<<<6912, 256, 0, stream>>>(
      x, xb, Wg, gates, cosp, sinp, cs, Wq, Wk, Wv, Wo,
      Wqkvt, Wqkvt + (size_t)1024 * 1024, Wqkvt + (size_t)1280 * 1024, Wot);

  gemm_qkv_fused<<<dim3(32, 12), 256, 0, stream>>>(xb, Wqkvt, cs, gates, ve,
                                                   qb, kb, vb);
  transpose_v<<<dim3(32, 4, 2), 256, 0, stream>>>(vb, vtb);

  attn_mfma<<<dim3(16, 16, 2), 256, 0, stream>>>(qb, kb, vtb, yb, win);

  gemm_wo<<<dim3(32, 8), 256, 0, stream>>>(yb, Wot, out);
}